// Round 5
// baseline (230.476 us; speedup 1.0000x reference)
//
#include <hip/hip_runtime.h>
#include <cstdint>
#include <cstddef>

// Problem constants
#define BB 32
#define SS 512
#define HH 768
#define WW 256
#define LL 8
#define NINTENT 26
#define NSLOT 121

typedef float f32x4 __attribute__((ext_vector_type(4)));
typedef __bf16 bf16x8 __attribute__((ext_vector_type(8)));

static __device__ __forceinline__ float bf2f(unsigned short u) {
    union { unsigned int i; float f; } x; x.i = ((unsigned int)u) << 16; return x.f;
}
static __device__ __forceinline__ unsigned short f2bf(float f) {
    union { float f; unsigned int i; } x; x.f = f;
    unsigned int r = (x.i + 0x7fffu + ((x.i >> 16) & 1u)) >> 16;
    return (unsigned short)r;
}

// async global->LDS, 16B per lane, wave-uniform LDS base + lane*16
static __device__ __forceinline__ void gload16(const void* g, void* l) {
    __builtin_amdgcn_global_load_lds(
        (const __attribute__((address_space(1))) void*)g,
        (__attribute__((address_space(3))) void*)l, 16, 0, 0);
}

#define MF(a, b, c) __builtin_amdgcn_mfma_f32_16x16x32_bf16((a), (b), (c), 0, 0, 0)

// ---------------- transpose + hi/lo split: Wk,Wq -> (hi,lo)T; Wv -> WvT ------
__global__ __launch_bounds__(256) void tpose_kernel(
    const float* __restrict__ Wk, const float* __restrict__ Wq,
    const float* __restrict__ Wv,
    unsigned short* __restrict__ WkT_hi, unsigned short* __restrict__ WkT_lo,
    unsigned short* __restrict__ WqT_hi, unsigned short* __restrict__ WqT_lo,
    unsigned short* __restrict__ WvT)
{
    __shared__ float tile[32][33];
    int mb = blockIdx.x / 576;
    int tb = blockIdx.x % 576;
    int tx = tb % 24, ty = tb / 24;
    const float* src = (mb == 0) ? Wk : (mb == 1) ? Wq : Wv;
    int c = threadIdx.x & 31, r = threadIdx.x >> 5;
#pragma unroll
    for (int j = 0; j < 4; j++)
        tile[r + 8 * j][c] = src[(ty * 32 + r + 8 * j) * HH + tx * 32 + c];
    __syncthreads();
#pragma unroll
    for (int j = 0; j < 4; j++) {
        int rr = r + 8 * j;
        float v = tile[c][rr];
        int o = (tx * 32 + rr) * HH + ty * 32 + c;
        unsigned short hi = f2bf(v);
        if (mb == 0) { WkT_hi[o] = hi; WkT_lo[o] = f2bf(v - bf2f(hi)); }
        else if (mb == 1) { WqT_hi[o] = hi; WqT_lo[o] = f2bf(v - bf2f(hi)); }
        else WvT[o] = hi;
    }
}

// ---------------- misc prep: Wcomb left (bf16 Ws, zero-pad), u = Wk^T bq, wsbv
__global__ __launch_bounds__(256) void misc_prep(
    const float* __restrict__ Ws, const float* __restrict__ Wk,
    const float* __restrict__ bq, const float* __restrict__ bv,
    unsigned short* __restrict__ Wcomb,   // [128][1536]
    float* __restrict__ u,                // [768]
    float* __restrict__ wsbv)             // [128]
{
    int bid = blockIdx.x, t = threadIdx.x;
    if (bid < 384) {
        int idx = bid * 256 + t;        // 0 .. 98303
        int row = idx / HH, col = idx % HH;
        Wcomb[row * 1536 + col] = (row < NSLOT) ? f2bf(Ws[row * HH + col]) : (unsigned short)0;
    } else if (bid == 384) {
        float a0 = 0.f, a1 = 0.f, a2 = 0.f;
        for (int o = 0; o < HH; o++) {
            float b = bq[o];
            a0 += b * Wk[o * HH + t];
            a1 += b * Wk[o * HH + t + 256];
            a2 += b * Wk[o * HH + t + 512];
        }
        u[t] = a0; u[t + 256] = a1; u[t + 512] = a2;
    } else {
        if (t < 128) {
            float s = 0.f;
            if (t < NSLOT)
                for (int j = 0; j < HH; j++) s += Ws[t * HH + j] * bv[j];
            wsbv[t] = (t < NSLOT) ? s : 0.f;
        }
    }
}

// ---------------- gather first rows -> slotA left half (bf16) ----------------
__global__ __launch_bounds__(256) void gather_first(
    const float* __restrict__ res_all, const int* __restrict__ starts,
    unsigned short* __restrict__ slotA)   // [8192][1536]
{
    int gw = blockIdx.x * 4 + (threadIdx.x >> 6);
    int lane = threadIdx.x & 63;
    int b = gw >> 8;
    int s0 = starts[gw];
    const float* src = res_all + (size_t)(b * SS + s0) * HH + lane * 12;
    unsigned short* dst = slotA + (size_t)gw * 1536 + lane * 12;
#pragma unroll
    for (int c = 0; c < 3; c++) {
        float4 v = *reinterpret_cast<const float4*>(&src[c * 4]);
        ushort4 o;
        o.x = f2bf(v.x); o.y = f2bf(v.y); o.z = f2bf(v.z); o.w = f2bf(v.w);
        *reinterpret_cast<ushort4*>(&dst[c * 4]) = o;
    }
}

// ---------------- generic 128x128 GEMM (m97-style), multi-pass ---------------
// C[m][n] = sum_p sum_k Ap[m][k]*Bp[n][k]  (+ colAdd[n]); out bf16 or f32.
struct GArgs {
    const uint4* A0; const uint4* A1; const uint4* A2;
    const uint4* B0; const uint4* B1; const uint4* B2;
    int lda, ldb;          // uint4 row pitch
    int npass, kc;         // kc = uint4 chunks per pass
    const float* colAdd;   // nullable
    unsigned short* Cb;    // bf16 out (nullable)
    float* Cf;             // f32 out (nullable)
    long ldc;              // element pitch of C
    int ntn;               // n tiles
    int swz;               // XCD chunked swizzle (grid % 8 == 0)
};

__global__ __launch_bounds__(256) void gemm128g(GArgs g) {
    __shared__ uint4 sA[512];
    __shared__ uint4 sB[512];

    int bid = blockIdx.x;
    if (g.swz) { int cpx = gridDim.x >> 3; bid = (bid & 7) * cpx + (bid >> 3); }
    int mt = bid / g.ntn, nt = bid % g.ntn;

    int t = threadIdx.x;
    int lane = t & 63, wave = t >> 6;
    int wm = wave >> 1, wn = wave & 1;
    int l16 = lane & 15, lk = lane >> 4;
    int srow = lane >> 2, schk = lane & 3;

    size_t arow = (size_t)(mt * 128 + wave * 32 + srow);
    size_t brow = (size_t)(nt * 128 + wave * 32 + srow);
    uint4* sA0 = &sA[wave * 128];
    uint4* sA1 = &sA[wave * 128 + 64];
    uint4* sB0 = &sB[wave * 128];
    uint4* sB1 = &sB[wave * 128 + 64];

    f32x4 acc[4][4] = {};

    for (int p = 0; p < g.npass; p++) {
        const uint4* Ab = (p == 0) ? g.A0 : (p == 1) ? g.A1 : g.A2;
        const uint4* Bb = (p == 0) ? g.B0 : (p == 1) ? g.B1 : g.B2;
        const uint4* Ag0 = Ab + arow * g.lda + schk;
        const uint4* Ag1 = Ag0 + (size_t)16 * g.lda;
        const uint4* Bg0 = Bb + brow * g.ldb + schk;
        const uint4* Bg1 = Bg0 + (size_t)16 * g.ldb;

        for (int k0 = 0; k0 < g.kc; k0 += 4) {
            gload16(Ag0 + k0, sA0);
            gload16(Ag1 + k0, sA1);
            gload16(Bg0 + k0, sB0);
            gload16(Bg1 + k0, sB1);
            __syncthreads();

            bf16x8 af[4], bfr[4];
#pragma unroll
            for (int i = 0; i < 4; i++)
                af[i] = *reinterpret_cast<const bf16x8*>(&sA[(wm * 64 + i * 16 + l16) * 4 + lk]);
#pragma unroll
            for (int j = 0; j < 4; j++)
                bfr[j] = *reinterpret_cast<const bf16x8*>(&sB[(wn * 64 + j * 16 + l16) * 4 + lk]);
#pragma unroll
            for (int i = 0; i < 4; i++)
#pragma unroll
                for (int j = 0; j < 4; j++)
                    acc[i][j] = MF(af[i], bfr[j], acc[i][j]);
            __syncthreads();
        }
    }

#pragma unroll
    for (int i = 0; i < 4; i++) {
#pragma unroll
        for (int j = 0; j < 4; j++) {
            int col = nt * 128 + wn * 64 + j * 16 + l16;
            float add = g.colAdd ? g.colAdd[col] : 0.f;
#pragma unroll
            for (int q = 0; q < 4; q++) {
                int row = mt * 128 + wm * 64 + i * 16 + lk * 4 + q;
                float v = acc[i][j][q] + add;
                if (g.Cb) g.Cb[(size_t)row * g.ldc + col] = f2bf(v);
                else      g.Cf[(size_t)row * g.ldc + col] = v;
            }
        }
    }
}

// ---------------- attention v2: scores = q'.x_k (f32), xbar -> slotA right ---
__global__ __launch_bounds__(256) void attn2_kernel(
    const float* __restrict__ qp,        // [8192][768] f32
    const float* __restrict__ res_all,   // [B*S][768] f32
    const int* __restrict__ starts,
    const int* __restrict__ lens,
    unsigned short* __restrict__ slotA)  // [8192][1536], writes cols 768..1535
{
    int bid = blockIdx.x;
    bid = (bid & 7) * 256 + (bid >> 3);              // 2048 = 8 x 256
    int gw = bid * 4 + (threadIdx.x >> 6);
    int lane = threadIdx.x & 63;
    int b = gw >> 8;
    int s0 = starts[gw];
    int sl = lens[gw];                               // 1..7, wave-uniform

    unsigned short* dst = slotA + (size_t)gw * 1536 + 768 + lane * 12;

    if (sl == 1) {                                   // word = first; xbar half = 0
        ushort4 z = {0, 0, 0, 0};
#pragma unroll
        for (int c = 0; c < 3; c++) *reinterpret_cast<ushort4*>(&dst[c * 4]) = z;
        return;
    }

    const float* qrow = qp + (size_t)gw * HH + lane * 12;
    float q[12];
#pragma unroll
    for (int c = 0; c < 3; c++) {
        float4 v = *reinterpret_cast<const float4*>(&qrow[c * 4]);
        q[c * 4 + 0] = v.x; q[c * 4 + 1] = v.y; q[c * 4 + 2] = v.z; q[c * 4 + 3] = v.w;
    }

    float scores[8];
#pragma unroll
    for (int k = 0; k < LL; k++) {
        if (k > sl) break;                           // uniform branch
        int s = s0 + k; if (s > SS - 1) s = SS - 1;
        const float* xr = res_all + (size_t)(b * SS + s) * HH + lane * 12;
        float partial = 0.f;
#pragma unroll
        for (int c = 0; c < 3; c++) {
            float4 v = *reinterpret_cast<const float4*>(&xr[c * 4]);
            partial += q[c * 4 + 0] * v.x + q[c * 4 + 1] * v.y
                     + q[c * 4 + 2] * v.z + q[c * 4 + 3] * v.w;
        }
#pragma unroll
        for (int off = 32; off > 0; off >>= 1) partial += __shfl_xor(partial, off);
        scores[k] = partial;
    }

    float m = -1e30f;
    for (int k = 0; k < LL; k++) if (k <= sl && scores[k] > m) m = scores[k];
    float p[8], ssum = 0.f;
    for (int k = 0; k < LL; k++) {
        p[k] = (k <= sl) ? __expf(scores[k] - m) : 0.f;
        ssum += p[k];
    }
    float inv = 1.f / ssum;

    float acc[12];
#pragma unroll
    for (int i = 0; i < 12; i++) acc[i] = 0.f;
    for (int k = 0; k < LL; k++) {
        if (k > sl) break;
        int s = s0 + k; if (s > SS - 1) s = SS - 1;
        const float* xr = res_all + (size_t)(b * SS + s) * HH + lane * 12;
        float wk = p[k] * inv;
#pragma unroll
        for (int c = 0; c < 3; c++) {
            float4 v = *reinterpret_cast<const float4*>(&xr[c * 4]);
            acc[c * 4 + 0] += wk * v.x; acc[c * 4 + 1] += wk * v.y;
            acc[c * 4 + 2] += wk * v.z; acc[c * 4 + 3] += wk * v.w;
        }
    }

#pragma unroll
    for (int c = 0; c < 3; c++) {
        ushort4 o;
        o.x = f2bf(acc[c * 4 + 0]); o.y = f2bf(acc[c * 4 + 1]);
        o.z = f2bf(acc[c * 4 + 2]); o.w = f2bf(acc[c * 4 + 3]);
        *reinterpret_cast<ushort4*>(&dst[c * 4]) = o;
    }
}

// ---------------- slot GEMM: out[8192][121] = slotA[8192][1536] . Wcomb^T ----
__global__ __launch_bounds__(256) void gemm_slot2(
    const uint4* __restrict__ A,    // [8192][192]
    const uint4* __restrict__ Bm,   // [128][192]
    const float* __restrict__ bias, // [121]
    const float* __restrict__ wsbv, // [128]
    const int* __restrict__ lens,   // [8192]
    float* __restrict__ Cf)         // [8192][121] f32
{
    __shared__ uint4 sA[256];   // 64 rows x 32 bf16
    __shared__ uint4 sB[512];   // 128 rows
    const int K8 = 192;

    int mt = blockIdx.x;
    int t = threadIdx.x;
    int lane = t & 63, wave = t >> 6;
    int wm = wave >> 1, wn = wave & 1;
    int l16 = lane & 15, lk = lane >> 4;

    int srow = lane >> 2, schk = lane & 3;
    const uint4* Ag  = A + (size_t)(mt * 64 + wave * 16 + srow) * K8 + schk;
    const uint4* Bg0 = Bm + (size_t)(wave * 32 + srow) * K8 + schk;
    const uint4* Bg1 = Bg0 + (size_t)16 * K8;
    uint4* sAp = &sA[wave * 64];
    uint4* sB0 = &sB[wave * 128];
    uint4* sB1 = &sB[wave * 128 + 64];

    f32x4 acc[2][4] = {};

    for (int k0 = 0; k0 < K8; k0 += 4) {
        gload16(Ag + k0, sAp);
        gload16(Bg0 + k0, sB0);
        gload16(Bg1 + k0, sB1);
        __syncthreads();

        bf16x8 af[2], bfr[4];
#pragma unroll
        for (int i = 0; i < 2; i++)
            af[i] = *reinterpret_cast<const bf16x8*>(&sA[(wm * 32 + i * 16 + l16) * 4 + lk]);
#pragma unroll
        for (int j = 0; j < 4; j++)
            bfr[j] = *reinterpret_cast<const bf16x8*>(&sB[(wn * 64 + j * 16 + l16) * 4 + lk]);
#pragma unroll
        for (int i = 0; i < 2; i++)
#pragma unroll
            for (int j = 0; j < 4; j++)
                acc[i][j] = MF(af[i], bfr[j], acc[i][j]);
        __syncthreads();
    }

#pragma unroll
    for (int i = 0; i < 2; i++) {
#pragma unroll
        for (int j = 0; j < 4; j++) {
            int col = wn * 64 + j * 16 + l16;
            if (col < NSLOT) {
                float bc = bias[col], wv = wsbv[col];
#pragma unroll
                for (int q = 0; q < 4; q++) {
                    int row = mt * 64 + wm * 32 + i * 16 + lk * 4 + q;
                    float fl = (lens[row] > 1) ? 1.f : 0.f;
                    Cf[(size_t)row * NSLOT + col] = acc[i][j][q] + bc + fl * wv;
                }
            }
        }
    }
}

// ---------------- res_id: tiny f32 GEMV ----------------
__global__ __launch_bounds__(256) void resid_kernel(
    const float* __restrict__ res, const float* __restrict__ w,
    const float* __restrict__ bias, float* __restrict__ out) {
    int bb = blockIdx.x;
    int t = threadIdx.x, lane = t & 63, wave = t >> 6;
    __shared__ float sres[HH];
    for (int i = t; i < HH; i += 256) sres[i] = res[bb * HH + i];
    __syncthreads();
    for (int o = wave; o < NINTENT; o += 4) {
        float s = 0.f;
        for (int i = lane; i < HH; i += 64) s += sres[i] * w[o * HH + i];
#pragma unroll
        for (int off = 32; off > 0; off >>= 1) s += __shfl_xor(s, off);
        if (lane == 0) out[bb * NINTENT + o] = s + bias[o];
    }
}

// ---------------- launch ----------------
extern "C" void kernel_launch(void* const* d_in, const int* in_sizes, int n_in,
                              void* d_out, int out_size, void* d_ws, size_t ws_size,
                              hipStream_t stream) {
    const float* res_all    = (const float*)d_in[0];
    const float* res        = (const float*)d_in[1];
    const int*   starts     = (const int*)d_in[2];
    const int*   lens       = (const int*)d_in[3];
    const float* Wsq_w      = (const float*)d_in[4];
    const float* Wsq_b      = (const float*)d_in[5];
    const float* Wsk_w      = (const float*)d_in[6];
    const float* Wsk_b      = (const float*)d_in[7];
    const float* Wsv_w      = (const float*)d_in[8];
    const float* Wsv_b      = (const float*)d_in[9];
    const float* lin_id_w   = (const float*)d_in[10];
    const float* lin_id_b   = (const float*)d_in[11];
    const float* lin_slot_w = (const float*)d_in[12];
    const float* lin_slot_b = (const float*)d_in[13];
    float* out = (float*)d_out;

    char* ws = (char*)d_ws;
    unsigned short* slotA  = (unsigned short*)(ws + 0);          // 8192x1536 bf16 (25.17 MB)
    float*          qp     = (float*)(ws + 25165824);            // 8192x768 f32 (25.17 MB)
    unsigned short* WkT_hi = (unsigned short*)(ws + 50331648);   // 768^2 bf16
    unsigned short* WkT_lo = (unsigned short*)(ws + 51511296);
    unsigned short* WqT_hi = (unsigned short*)(ws + 52690944);
    unsigned short* WqT_lo = (unsigned short*)(ws + 53870592);
    unsigned short* WvT    = (unsigned short*)(ws + 55050240);
    unsigned short* Pb     = (unsigned short*)(ws + 56229888);   // 768^2 bf16
    unsigned short* Wcomb  = (unsigned short*)(ws + 57409536);   // 128x1536 bf16
    float*          u      = (float*)(ws + 57802752);            // 768 f32
    float*          wsbv   = (float*)(ws + 57805824);            // 128 f32

    // 1) transposes + hi/lo splits (Wk, Wq, Wv)
    tpose_kernel<<<1728, 256, 0, stream>>>(Wsk_w, Wsq_w, Wsv_w,
                                           WkT_hi, WkT_lo, WqT_hi, WqT_lo, WvT);

    // 2) misc prep: Wcomb left (bf16 Ws + zero pad), u = Wk^T bq, wsbv = Ws bv
    misc_prep<<<386, 256, 0, stream>>>(lin_slot_w, Wsk_w, Wsq_b, Wsv_b,
                                       Wcomb, u, wsbv);

    // 3) gather first rows -> slotA left half
    gather_first<<<2048, 256, 0, stream>>>(res_all, starts, slotA);

    // 4) G1: Pb = Wk^T Wq (split: hi.hi + lo.hi + hi.lo), M=N=768
    {
        GArgs g = {};
        g.A0 = (const uint4*)WkT_hi; g.A1 = (const uint4*)WkT_lo; g.A2 = (const uint4*)WkT_hi;
        g.B0 = (const uint4*)WqT_hi; g.B1 = (const uint4*)WqT_hi; g.B2 = (const uint4*)WqT_lo;
        g.lda = 96; g.ldb = 96; g.npass = 3; g.kc = 96;
        g.colAdd = nullptr; g.Cb = Pb; g.Cf = nullptr; g.ldc = 768;
        g.ntn = 6; g.swz = 0;
        gemm128g<<<36, 256, 0, stream>>>(g);
    }

    // 5) G2: Wcomb right = Ws . WvT^T  (M=128, N=768)
    {
        GArgs g = {};
        g.A0 = (const uint4*)Wcomb; g.A1 = g.A0; g.A2 = g.A0;
        g.B0 = (const uint4*)WvT;   g.B1 = g.B0; g.B2 = g.B0;
        g.lda = 192; g.ldb = 96; g.npass = 1; g.kc = 96;
        g.colAdd = nullptr; g.Cb = Wcomb + 768; g.Cf = nullptr; g.ldc = 1536;
        g.ntn = 6; g.swz = 0;
        gemm128g<<<6, 256, 0, stream>>>(g);
    }

    // 6) G3: qp = slotA_left . Pb^T + u  (M=8192, N=768, f32 out)
    {
        GArgs g = {};
        g.A0 = (const uint4*)slotA; g.A1 = g.A0; g.A2 = g.A0;
        g.B0 = (const uint4*)Pb;    g.B1 = g.B0; g.B2 = g.B0;
        g.lda = 192; g.ldb = 96; g.npass = 1; g.kc = 96;
        g.colAdd = u; g.Cb = nullptr; g.Cf = qp; g.ldc = 768;
        g.ntn = 6; g.swz = 1;
        gemm128g<<<384, 256, 0, stream>>>(g);
    }

    // 7) attention: scores/softmax/xbar -> slotA right half
    attn2_kernel<<<2048, 256, 0, stream>>>(qp, res_all, starts, lens, slotA);

    // 8) slot GEMM: out_sf = slotA . Wcomb^T + b + (sl>1)*wsbv
    gemm_slot2<<<128, 256, 0, stream>>>((const uint4*)slotA, (const uint4*)Wcomb,
                                        lin_slot_b, wsbv, lens, out + 832);

    // 9) res_id
    resid_kernel<<<BB, 256, 0, stream>>>(res, lin_id_w, lin_id_b, out);
}

// Round 6
// 135.431 us; speedup vs baseline: 1.7018x; 1.7018x over previous
//
#include <hip/hip_runtime.h>
#include <cstdint>
#include <cstddef>

// Problem constants
#define BB 32
#define SS 512
#define HH 768
#define WW 256
#define LL 8
#define NINTENT 26
#define NSLOT 121

typedef float f32x4 __attribute__((ext_vector_type(4)));
typedef __bf16 bf16x8 __attribute__((ext_vector_type(8)));

static __device__ __forceinline__ float bf2f(unsigned short u) {
    union { unsigned int i; float f; } x; x.i = ((unsigned int)u) << 16; return x.f;
}
static __device__ __forceinline__ unsigned short f2bf(float f) {
    union { float f; unsigned int i; } x; x.f = f;
    unsigned int r = (x.i + 0x7fffu + ((x.i >> 16) & 1u)) >> 16;
    return (unsigned short)r;
}

// async global->LDS, 16B per lane, wave-uniform LDS base + lane*16
static __device__ __forceinline__ void gload16(const void* g, void* l) {
    __builtin_amdgcn_global_load_lds(
        (const __attribute__((address_space(1))) void*)g,
        (__attribute__((address_space(3))) void*)l, 16, 0, 0);
}

#define MF(a, b, c) __builtin_amdgcn_mfma_f32_16x16x32_bf16((a), (b), (c), 0, 0, 0)

// ================= L1: mega prep =================
// blocks [0,1728): transpose+hi/lo split of Wk/Wq/Wv; mb==0 also emits u partials
// blocks [1728,2112): Wcomb left copy (bf16 Ws, zero pad) + wsbv partials
// blocks [2112,4160): gather first rows -> slotA left half
// blocks [4160,4192): res_id GEMV
__global__ __launch_bounds__(256) void prep_all(
    const float* __restrict__ Wk, const float* __restrict__ Wq,
    const float* __restrict__ Wv, const float* __restrict__ Ws,
    const float* __restrict__ bq, const float* __restrict__ bv,
    const float* __restrict__ res_all, const int* __restrict__ starts,
    const float* __restrict__ res, const float* __restrict__ id_w,
    const float* __restrict__ id_b,
    unsigned short* __restrict__ WkT_hi, unsigned short* __restrict__ WkT_lo,
    unsigned short* __restrict__ WqT_hi, unsigned short* __restrict__ WqT_lo,
    unsigned short* __restrict__ WvT, unsigned short* __restrict__ Wcomb,
    float* __restrict__ u_part,     // [24][768]
    float* __restrict__ wsbv_part,  // [3][128]
    unsigned short* __restrict__ slotA,  // [8192][1536]
    float* __restrict__ out)
{
    int bid = blockIdx.x;
    int t = threadIdx.x;

    if (bid < 1728) {
        __shared__ float tile[32][33];
        __shared__ float red[256];
        int mb = bid / 576, tb = bid % 576;
        int tx = tb % 24, ty = tb / 24;
        const float* src = (mb == 0) ? Wk : (mb == 1) ? Wq : Wv;
        int c = t & 31, r = t >> 5;
#pragma unroll
        for (int j = 0; j < 4; j++)
            tile[r + 8 * j][c] = src[(ty * 32 + r + 8 * j) * HH + tx * 32 + c];
        __syncthreads();
#pragma unroll
        for (int j = 0; j < 4; j++) {
            int rr = r + 8 * j;
            float v = tile[c][rr];
            int o = (tx * 32 + rr) * HH + ty * 32 + c;
            unsigned short hi = f2bf(v);
            if (mb == 0) { WkT_hi[o] = hi; WkT_lo[o] = f2bf(v - bf2f(hi)); }
            else if (mb == 1) { WqT_hi[o] = hi; WqT_lo[o] = f2bf(v - bf2f(hi)); }
            else WvT[o] = hi;
        }
        if (mb == 0) {  // u partials: u_part[ty][col] = sum_r bq[ty*32+r]*Wk[r][col]
            float partial = 0.f;
#pragma unroll
            for (int j = 0; j < 4; j++) {
                int rr = r + 8 * j;
                partial += bq[ty * 32 + rr] * tile[rr][c];
            }
            red[t] = partial;
            __syncthreads();
            if (t < 32) {
                float s = 0.f;
#pragma unroll
                for (int k = 0; k < 8; k++) s += red[k * 32 + t];
                u_part[ty * HH + tx * 32 + t] = s;
            }
        }
    } else if (bid < 2112) {
        __shared__ float wred[4];
        int bid2 = bid - 1728;
        int idx = bid2 * 256 + t;         // 0..98303 over 128x768
        int row = idx / HH, col = idx % HH;
        float v = (row < NSLOT) ? Ws[row * HH + col] : 0.f;
        Wcomb[row * 1536 + col] = f2bf(v);
        // wsbv partial: this block covers one 256-col chunk of one row
        float pv = v * bv[col];
        int lane = t & 63, wave = t >> 6;
#pragma unroll
        for (int off = 32; off > 0; off >>= 1) pv += __shfl_xor(pv, off);
        if (lane == 0) wred[wave] = pv;
        __syncthreads();
        if (t == 0)
            wsbv_part[(bid2 % 3) * 128 + row] = wred[0] + wred[1] + wred[2] + wred[3];
    } else if (bid < 4160) {
        int gw = (bid - 2112) * 4 + (t >> 6);
        int lane = t & 63;
        int b = gw >> 8;
        int s0 = starts[gw];
        const float* src = res_all + (size_t)(b * SS + s0) * HH + lane * 12;
        unsigned short* dst = slotA + (size_t)gw * 1536 + lane * 12;
#pragma unroll
        for (int c2 = 0; c2 < 3; c2++) {
            float4 v = *reinterpret_cast<const float4*>(&src[c2 * 4]);
            ushort4 o;
            o.x = f2bf(v.x); o.y = f2bf(v.y); o.z = f2bf(v.z); o.w = f2bf(v.w);
            *reinterpret_cast<ushort4*>(&dst[c2 * 4]) = o;
        }
    } else {
        __shared__ float sres[HH];
        int bb = bid - 4160;
        int lane = t & 63, wave = t >> 6;
        for (int i = t; i < HH; i += 256) sres[i] = res[bb * HH + i];
        __syncthreads();
        for (int o = wave; o < NINTENT; o += 4) {
            float s = 0.f;
            for (int i = lane; i < HH; i += 64) s += sres[i] * id_w[o * HH + i];
#pragma unroll
            for (int off = 32; off > 0; off >>= 1) s += __shfl_xor(s, off);
            if (lane == 0) out[bb * NINTENT + o] = s + id_b[o];
        }
    }
}

// ================= L2: weight GEMMs in one launch =================
// blocks [0,108): G1 partials  Ppart[p] = (p-selected A).(p-selected B)^T, f32
//                 p0: hi.hi  p1: lo.hi  p2: hi.lo   (36 tiles each)
// blocks [108,114): G2: WcombR = Wcomb_left . WvT^T (bf16, ldc 1536)
__global__ __launch_bounds__(256) void gemm_weights(
    const uint4* __restrict__ WkT_hi, const uint4* __restrict__ WkT_lo,
    const uint4* __restrict__ WqT_hi, const uint4* __restrict__ WqT_lo,
    const uint4* __restrict__ WvT, const uint4* __restrict__ Wcomb,
    float* __restrict__ Ppart,           // [3][768][768]
    unsigned short* __restrict__ WcombR) // Wcomb + 768
{
    __shared__ uint4 sA[512];
    __shared__ uint4 sB[512];

    int bid = blockIdx.x;
    bool g2 = (bid >= 108);
    const uint4 *Ab, *Bb;
    int lda, ldb, mt, nt, p = 0;
    if (!g2) {
        int tile = bid % 36; p = bid / 36;
        mt = tile / 6; nt = tile % 6;
        Ab = (p == 1) ? WkT_lo : WkT_hi;
        Bb = (p == 2) ? WqT_lo : WqT_hi;
        lda = 96; ldb = 96;
    } else {
        mt = 0; nt = bid - 108;
        Ab = Wcomb; Bb = WvT; lda = 192; ldb = 96;
    }

    int t = threadIdx.x;
    int lane = t & 63, wave = t >> 6;
    int wm = wave >> 1, wn = wave & 1;
    int l16 = lane & 15, lk = lane >> 4;
    int srow = lane >> 2, schk = lane & 3;

    const uint4* Ag0 = Ab + (size_t)(mt * 128 + wave * 32 + srow) * lda + schk;
    const uint4* Ag1 = Ag0 + (size_t)16 * lda;
    const uint4* Bg0 = Bb + (size_t)(nt * 128 + wave * 32 + srow) * ldb + schk;
    const uint4* Bg1 = Bg0 + (size_t)16 * ldb;
    uint4* sA0 = &sA[wave * 128];
    uint4* sA1 = &sA[wave * 128 + 64];
    uint4* sB0 = &sB[wave * 128];
    uint4* sB1 = &sB[wave * 128 + 64];

    f32x4 acc[4][4] = {};

    for (int k0 = 0; k0 < 96; k0 += 4) {
        gload16(Ag0 + k0, sA0);
        gload16(Ag1 + k0, sA1);
        gload16(Bg0 + k0, sB0);
        gload16(Bg1 + k0, sB1);
        __syncthreads();
        bf16x8 af[4], bfr[4];
#pragma unroll
        for (int i = 0; i < 4; i++)
            af[i] = *reinterpret_cast<const bf16x8*>(&sA[(wm * 64 + i * 16 + l16) * 4 + lk]);
#pragma unroll
        for (int j = 0; j < 4; j++)
            bfr[j] = *reinterpret_cast<const bf16x8*>(&sB[(wn * 64 + j * 16 + l16) * 4 + lk]);
#pragma unroll
        for (int i = 0; i < 4; i++)
#pragma unroll
            for (int j = 0; j < 4; j++)
                acc[i][j] = MF(af[i], bfr[j], acc[i][j]);
        __syncthreads();
    }

#pragma unroll
    for (int i = 0; i < 4; i++) {
#pragma unroll
        for (int j = 0; j < 4; j++) {
            int col = nt * 128 + wn * 64 + j * 16 + l16;
#pragma unroll
            for (int q = 0; q < 4; q++) {
                int row = mt * 128 + wm * 64 + i * 16 + lk * 4 + q;
                float v = acc[i][j][q];
                if (!g2) Ppart[(size_t)p * 589824 + (size_t)row * HH + col] = v;
                else     WcombR[(size_t)row * 1536 + col] = f2bf(v);
            }
        }
    }
}

// ================= L3: sums =================
__global__ __launch_bounds__(256) void psum_kernel(
    const float4* __restrict__ Ppart, ushort4* __restrict__ Pb,
    const float* __restrict__ u_part, float* __restrict__ u,
    const float* __restrict__ wsbv_part, float* __restrict__ wsbv)
{
    int bid = blockIdx.x, t = threadIdx.x;
    if (bid < 576) {
        int i = bid * 256 + t;   // float4 index, 147456 total
        float4 a = Ppart[i], b = Ppart[i + 147456], c = Ppart[i + 294912];
        ushort4 o;
        o.x = f2bf(a.x + b.x + c.x); o.y = f2bf(a.y + b.y + c.y);
        o.z = f2bf(a.z + b.z + c.z); o.w = f2bf(a.w + b.w + c.w);
        Pb[i] = o;
    } else if (bid < 579) {
        int c = (bid - 576) * 256 + t;
        float s = 0.f;
#pragma unroll
        for (int ty = 0; ty < 24; ty++) s += u_part[ty * HH + c];
        u[c] = s;
    } else if (t < 128) {
        wsbv[t] = wsbv_part[t] + wsbv_part[128 + t] + wsbv_part[256 + t];
    }
}

// ================= L4: qp = slotA_left . Pb^T + u  (f32 out) =================
__global__ __launch_bounds__(256) void gemm_qp(
    const uint4* __restrict__ A,   // slotA [8192][192]
    const uint4* __restrict__ Bm,  // Pb [768][96]
    const float* __restrict__ u,
    float* __restrict__ qp)        // [8192][768]
{
    __shared__ uint4 sA[512];
    __shared__ uint4 sB[512];

    int bid = blockIdx.x;
    bid = (bid & 7) * 48 + (bid >> 3);   // 384 = 8 x 48
    int mt = bid / 6, nt = bid % 6;

    int t = threadIdx.x;
    int lane = t & 63, wave = t >> 6;
    int wm = wave >> 1, wn = wave & 1;
    int l16 = lane & 15, lk = lane >> 4;
    int srow = lane >> 2, schk = lane & 3;

    const uint4* Ag0 = A + (size_t)(mt * 128 + wave * 32 + srow) * 192 + schk;
    const uint4* Ag1 = Ag0 + (size_t)16 * 192;
    const uint4* Bg0 = Bm + (size_t)(nt * 128 + wave * 32 + srow) * 96 + schk;
    const uint4* Bg1 = Bg0 + (size_t)16 * 96;
    uint4* sA0 = &sA[wave * 128];
    uint4* sA1 = &sA[wave * 128 + 64];
    uint4* sB0 = &sB[wave * 128];
    uint4* sB1 = &sB[wave * 128 + 64];

    f32x4 acc[4][4] = {};

    for (int k0 = 0; k0 < 96; k0 += 4) {
        gload16(Ag0 + k0, sA0);
        gload16(Ag1 + k0, sA1);
        gload16(Bg0 + k0, sB0);
        gload16(Bg1 + k0, sB1);
        __syncthreads();
        bf16x8 af[4], bfr[4];
#pragma unroll
        for (int i = 0; i < 4; i++)
            af[i] = *reinterpret_cast<const bf16x8*>(&sA[(wm * 64 + i * 16 + l16) * 4 + lk]);
#pragma unroll
        for (int j = 0; j < 4; j++)
            bfr[j] = *reinterpret_cast<const bf16x8*>(&sB[(wn * 64 + j * 16 + l16) * 4 + lk]);
#pragma unroll
        for (int i = 0; i < 4; i++)
#pragma unroll
            for (int j = 0; j < 4; j++)
                acc[i][j] = MF(af[i], bfr[j], acc[i][j]);
        __syncthreads();
    }

#pragma unroll
    for (int i = 0; i < 4; i++) {
#pragma unroll
        for (int j = 0; j < 4; j++) {
            int col = nt * 128 + wn * 64 + j * 16 + l16;
            float add = u[col];
#pragma unroll
            for (int q = 0; q < 4; q++) {
                int row = mt * 128 + wm * 64 + i * 16 + lk * 4 + q;
                qp[(size_t)row * HH + col] = acc[i][j][q] + add;
            }
        }
    }
}

// ================= L5: attention (scores f32, xbar -> slotA right) ==========
__global__ __launch_bounds__(256) void attn2_kernel(
    const float* __restrict__ qp,        // [8192][768] f32
    const float* __restrict__ res_all,   // [B*S][768] f32
    const int* __restrict__ starts,
    const int* __restrict__ lens,
    unsigned short* __restrict__ slotA)  // [8192][1536], writes cols 768..1535
{
    int bid = blockIdx.x;
    bid = (bid & 7) * 256 + (bid >> 3);              // 2048 = 8 x 256
    int gw = bid * 4 + (threadIdx.x >> 6);
    int lane = threadIdx.x & 63;
    int b = gw >> 8;
    int s0 = starts[gw];
    int sl = lens[gw];                               // 1..7, wave-uniform

    unsigned short* dst = slotA + (size_t)gw * 1536 + 768 + lane * 12;

    if (sl == 1) {                                   // word = first; xbar half = 0
        ushort4 z = {0, 0, 0, 0};
#pragma unroll
        for (int c = 0; c < 3; c++) *reinterpret_cast<ushort4*>(&dst[c * 4]) = z;
        return;
    }

    const float* qrow = qp + (size_t)gw * HH + lane * 12;
    float q[12];
#pragma unroll
    for (int c = 0; c < 3; c++) {
        float4 v = *reinterpret_cast<const float4*>(&qrow[c * 4]);
        q[c * 4 + 0] = v.x; q[c * 4 + 1] = v.y; q[c * 4 + 2] = v.z; q[c * 4 + 3] = v.w;
    }

    float scores[8];
#pragma unroll
    for (int k = 0; k < LL; k++) {
        if (k > sl) break;                           // uniform branch
        int s = s0 + k; if (s > SS - 1) s = SS - 1;
        const float* xr = res_all + (size_t)(b * SS + s) * HH + lane * 12;
        float partial = 0.f;
#pragma unroll
        for (int c = 0; c < 3; c++) {
            float4 v = *reinterpret_cast<const float4*>(&xr[c * 4]);
            partial += q[c * 4 + 0] * v.x + q[c * 4 + 1] * v.y
                     + q[c * 4 + 2] * v.z + q[c * 4 + 3] * v.w;
        }
#pragma unroll
        for (int off = 32; off > 0; off >>= 1) partial += __shfl_xor(partial, off);
        scores[k] = partial;
    }

    float m = -1e30f;
    for (int k = 0; k < LL; k++) if (k <= sl && scores[k] > m) m = scores[k];
    float p[8], ssum = 0.f;
    for (int k = 0; k < LL; k++) {
        p[k] = (k <= sl) ? __expf(scores[k] - m) : 0.f;
        ssum += p[k];
    }
    float inv = 1.f / ssum;

    float acc[12];
#pragma unroll
    for (int i = 0; i < 12; i++) acc[i] = 0.f;
    for (int k = 0; k < LL; k++) {
        if (k > sl) break;
        int s = s0 + k; if (s > SS - 1) s = SS - 1;
        const float* xr = res_all + (size_t)(b * SS + s) * HH + lane * 12;
        float wk = p[k] * inv;
#pragma unroll
        for (int c = 0; c < 3; c++) {
            float4 v = *reinterpret_cast<const float4*>(&xr[c * 4]);
            acc[c * 4 + 0] += wk * v.x; acc[c * 4 + 1] += wk * v.y;
            acc[c * 4 + 2] += wk * v.z; acc[c * 4 + 3] += wk * v.w;
        }
    }

#pragma unroll
    for (int c = 0; c < 3; c++) {
        ushort4 o;
        o.x = f2bf(acc[c * 4 + 0]); o.y = f2bf(acc[c * 4 + 1]);
        o.z = f2bf(acc[c * 4 + 2]); o.w = f2bf(acc[c * 4 + 3]);
        *reinterpret_cast<ushort4*>(&dst[c * 4]) = o;
    }
}

// ================= L6: slot GEMM: out = slotA . Wcomb^T + b + [sl>1]*wsbv ====
__global__ __launch_bounds__(256) void gemm_slot2(
    const uint4* __restrict__ A,    // [8192][192]
    const uint4* __restrict__ Bm,   // [128][192]
    const float* __restrict__ bias, // [121]
    const float* __restrict__ wsbv, // [128]
    const int* __restrict__ lens,   // [8192]
    float* __restrict__ Cf)         // [8192][121] f32
{
    __shared__ uint4 sA[256];   // 64 rows x 32 bf16
    __shared__ uint4 sB[512];   // 128 rows
    const int K8 = 192;

    int mt = blockIdx.x;
    int t = threadIdx.x;
    int lane = t & 63, wave = t >> 6;
    int wm = wave >> 1, wn = wave & 1;
    int l16 = lane & 15, lk = lane >> 4;

    int srow = lane >> 2, schk = lane & 3;
    const uint4* Ag  = A + (size_t)(mt * 64 + wave * 16 + srow) * K8 + schk;
    const uint4* Bg0 = Bm + (size_t)(wave * 32 + srow) * K8 + schk;
    const uint4* Bg1 = Bg0 + (size_t)16 * K8;
    uint4* sAp = &sA[wave * 64];
    uint4* sB0 = &sB[wave * 128];
    uint4* sB1 = &sB[wave * 128 + 64];

    f32x4 acc[2][4] = {};

    for (int k0 = 0; k0 < K8; k0 += 4) {
        gload16(Ag + k0, sAp);
        gload16(Bg0 + k0, sB0);
        gload16(Bg1 + k0, sB1);
        __syncthreads();

        bf16x8 af[2], bfr[4];
#pragma unroll
        for (int i = 0; i < 2; i++)
            af[i] = *reinterpret_cast<const bf16x8*>(&sA[(wm * 32 + i * 16 + l16) * 4 + lk]);
#pragma unroll
        for (int j = 0; j < 4; j++)
            bfr[j] = *reinterpret_cast<const bf16x8*>(&sB[(wn * 64 + j * 16 + l16) * 4 + lk]);
#pragma unroll
        for (int i = 0; i < 2; i++)
#pragma unroll
            for (int j = 0; j < 4; j++)
                acc[i][j] = MF(af[i], bfr[j], acc[i][j]);
        __syncthreads();
    }

#pragma unroll
    for (int i = 0; i < 2; i++) {
#pragma unroll
        for (int j = 0; j < 4; j++) {
            int col = wn * 64 + j * 16 + l16;
            if (col < NSLOT) {
                float bc = bias[col], wv = wsbv[col];
#pragma unroll
                for (int q = 0; q < 4; q++) {
                    int row = mt * 64 + wm * 32 + i * 16 + lk * 4 + q;
                    float fl = (lens[row] > 1) ? 1.f : 0.f;
                    Cf[(size_t)row * NSLOT + col] = acc[i][j][q] + bc + fl * wv;
                }
            }
        }
    }
}

// ---------------- launch ----------------
extern "C" void kernel_launch(void* const* d_in, const int* in_sizes, int n_in,
                              void* d_out, int out_size, void* d_ws, size_t ws_size,
                              hipStream_t stream) {
    const float* res_all    = (const float*)d_in[0];
    const float* res        = (const float*)d_in[1];
    const int*   starts     = (const int*)d_in[2];
    const int*   lens       = (const int*)d_in[3];
    const float* Wsq_w      = (const float*)d_in[4];
    const float* Wsq_b      = (const float*)d_in[5];
    const float* Wsk_w      = (const float*)d_in[6];
    const float* Wsk_b      = (const float*)d_in[7];
    const float* Wsv_w      = (const float*)d_in[8];
    const float* Wsv_b      = (const float*)d_in[9];
    const float* lin_id_w   = (const float*)d_in[10];
    const float* lin_id_b   = (const float*)d_in[11];
    const float* lin_slot_w = (const float*)d_in[12];
    const float* lin_slot_b = (const float*)d_in[13];
    float* out = (float*)d_out;
    (void)Wsk_b;  // softmax-invariant (constant over k)

    char* ws = (char*)d_ws;
    unsigned short* slotA     = (unsigned short*)(ws + 0);          // 8192x1536 bf16
    float*          qp        = (float*)(ws + 25165824);            // 8192x768 f32
    unsigned short* WkT_hi    = (unsigned short*)(ws + 50331648);
    unsigned short* WkT_lo    = (unsigned short*)(ws + 51511296);
    unsigned short* WqT_hi    = (unsigned short*)(ws + 52690944);
    unsigned short* WqT_lo    = (unsigned short*)(ws + 53870592);
    unsigned short* WvT       = (unsigned short*)(ws + 55050240);
    unsigned short* Pb        = (unsigned short*)(ws + 56229888);   // 768^2 bf16
    unsigned short* Wcomb     = (unsigned short*)(ws + 57409536);   // 128x1536 bf16
    float*          u         = (float*)(ws + 57802752);            // 768
    float*          wsbv      = (float*)(ws + 57805824);            // 128
    float*          u_part    = (float*)(ws + 57806336);            // 24x768
    float*          wsbv_part = (float*)(ws + 57880064);            // 3x128
    float*          Ppart     = (float*)(ws + 57881600);            // 3x768x768 f32

    // L1: mega prep (transpose/split + Wcomb left + gather + res_id)
    prep_all<<<4192, 256, 0, stream>>>(
        Wsk_w, Wsq_w, Wsv_w, lin_slot_w, Wsq_b, Wsv_b,
        res_all, starts, res, lin_id_w, lin_id_b,
        WkT_hi, WkT_lo, WqT_hi, WqT_lo, WvT, Wcomb,
        u_part, wsbv_part, slotA, out);

    // L2: weight GEMMs (G1 partials x3 + G2) in one launch
    gemm_weights<<<114, 256, 0, stream>>>(
        (const uint4*)WkT_hi, (const uint4*)WkT_lo,
        (const uint4*)WqT_hi, (const uint4*)WqT_lo,
        (const uint4*)WvT, (const uint4*)Wcomb,
        Ppart, Wcomb + 768);

    // L3: reductions (Pb = sum Ppart -> bf16, u, wsbv)
    psum_kernel<<<580, 256, 0, stream>>>(
        (const float4*)Ppart, (ushort4*)Pb, u_part, u, wsbv_part, wsbv);

    // L4: qp = slotA_left . Pb^T + u
    gemm_qp<<<384, 256, 0, stream>>>((const uint4*)slotA, (const uint4*)Pb, u, qp);

    // L5: attention -> slotA right half
    attn2_kernel<<<2048, 256, 0, stream>>>(qp, res_all, starts, lens, slotA);

    // L6: slot GEMM -> out
    gemm_slot2<<<128, 256, 0, stream>>>((const uint4*)slotA, (const uint4*)Wcomb,
                                        lin_slot_b, wsbv, lens, out + 832);
}

// Round 7
// 121.059 us; speedup vs baseline: 1.9038x; 1.1187x over previous
//
#include <hip/hip_runtime.h>
#include <cstdint>
#include <cstddef>

// Problem constants
#define BB 32
#define SS 512
#define HH 768
#define WW 256
#define LL 8
#define NINTENT 26
#define NSLOT 121

typedef float f32x4 __attribute__((ext_vector_type(4)));
typedef __bf16 bf16x8 __attribute__((ext_vector_type(8)));

static __device__ __forceinline__ float bf2f(unsigned short u) {
    union { unsigned int i; float f; } x; x.i = ((unsigned int)u) << 16; return x.f;
}
static __device__ __forceinline__ unsigned short f2bf(float f) {
    union { float f; unsigned int i; } x; x.f = f;
    unsigned int r = (x.i + 0x7fffu + ((x.i >> 16) & 1u)) >> 16;
    return (unsigned short)r;
}

// async global->LDS, 16B per lane, wave-uniform LDS base + lane*16
static __device__ __forceinline__ void gload16(const void* g, void* l) {
    __builtin_amdgcn_global_load_lds(
        (const __attribute__((address_space(1))) void*)g,
        (__attribute__((address_space(3))) void*)l, 16, 0, 0);
}

#define MF(a, b, c) __builtin_amdgcn_mfma_f32_16x16x32_bf16((a), (b), (c), 0, 0, 0)

// ================= L1: mega prep =================
// [0,432):    64x64 transpose + hi/lo split (Wk,Wq) / hi (Wv); Wk also u-partials
// [432,816):  Wcomb left copy (bf16 Ws, zero pad) + wsbv partials
// [816,2864): gather first rows -> slotA left half
// [2864,2896): res_id GEMV
__global__ __launch_bounds__(256) void prep_all(
    const float* __restrict__ Wk, const float* __restrict__ Wq,
    const float* __restrict__ Wv, const float* __restrict__ Ws,
    const float* __restrict__ bq, const float* __restrict__ bv,
    const float* __restrict__ res_all, const int* __restrict__ starts,
    const float* __restrict__ res, const float* __restrict__ id_w,
    const float* __restrict__ id_b,
    unsigned short* __restrict__ WkT_hi, unsigned short* __restrict__ WkT_lo,
    unsigned short* __restrict__ WqT_hi, unsigned short* __restrict__ WqT_lo,
    unsigned short* __restrict__ WvT, unsigned short* __restrict__ Wcomb,
    float* __restrict__ u_part,     // [12][768]
    float* __restrict__ wsbv_part,  // [3][128]
    unsigned short* __restrict__ slotA,  // [8192][1536]
    float* __restrict__ out)
{
    int bid = blockIdx.x;
    int t = threadIdx.x;

    if (bid < 432) {
        __shared__ float tl[64][65];
        int mb = bid / 144, tb = bid % 144;
        int tx = tb % 12, ty = tb / 12;
        const float* src = (mb == 0) ? Wk : (mb == 1) ? Wq : Wv;
        int rr = t >> 4, c4 = (t & 15) * 4;
#pragma unroll
        for (int j = 0; j < 4; j++) {
            float4 v = *reinterpret_cast<const float4*>(
                &src[(size_t)(ty * 64 + rr + 16 * j) * HH + tx * 64 + c4]);
            tl[rr + 16 * j][c4 + 0] = v.x; tl[rr + 16 * j][c4 + 1] = v.y;
            tl[rr + 16 * j][c4 + 2] = v.z; tl[rr + 16 * j][c4 + 3] = v.w;
        }
        __syncthreads();
        int il = t >> 4, o4 = (t & 15) * 4;
        unsigned short* dhi = (mb == 0) ? WkT_hi : (mb == 1) ? WqT_hi : WvT;
        unsigned short* dlo = (mb == 0) ? WkT_lo : WqT_lo;  // unused when mb==2
#pragma unroll
        for (int j = 0; j < 4; j++) {
            int i = il + 16 * j;
            float v0 = tl[o4 + 0][i], v1 = tl[o4 + 1][i];
            float v2 = tl[o4 + 2][i], v3 = tl[o4 + 3][i];
            size_t off = (size_t)(tx * 64 + i) * HH + ty * 64 + o4;
            ushort4 h;
            h.x = f2bf(v0); h.y = f2bf(v1); h.z = f2bf(v2); h.w = f2bf(v3);
            *reinterpret_cast<ushort4*>(&dhi[off]) = h;
            if (mb < 2) {
                ushort4 l;
                l.x = f2bf(v0 - bf2f(h.x)); l.y = f2bf(v1 - bf2f(h.y));
                l.z = f2bf(v2 - bf2f(h.z)); l.w = f2bf(v3 - bf2f(h.w));
                *reinterpret_cast<ushort4*>(&dlo[off]) = l;
            }
        }
        if (mb == 0) {  // u_part[ty][tx*64+c] = sum_r bq[ty*64+r]*Wk[ty*64+r][tx*64+c]
            int c = t >> 2, q = t & 3;
            float s = 0.f;
#pragma unroll
            for (int r = 0; r < 16; r++)
                s += bq[ty * 64 + q * 16 + r] * tl[q * 16 + r][c];
            s += __shfl_xor(s, 1);
            s += __shfl_xor(s, 2);
            if (q == 0) u_part[ty * HH + tx * 64 + c] = s;
        }
    } else if (bid < 816) {
        __shared__ float wred[4];
        int bid2 = bid - 432;
        int idx = bid2 * 256 + t;         // 0..98303 over 128x768
        int row = idx / HH, col = idx % HH;
        float v = (row < NSLOT) ? Ws[row * HH + col] : 0.f;
        Wcomb[row * 1536 + col] = f2bf(v);
        float pv = v * bv[col];
        int lane = t & 63, wave = t >> 6;
#pragma unroll
        for (int off = 32; off > 0; off >>= 1) pv += __shfl_xor(pv, off);
        if (lane == 0) wred[wave] = pv;
        __syncthreads();
        if (t == 0)
            wsbv_part[(bid2 % 3) * 128 + row] = wred[0] + wred[1] + wred[2] + wred[3];
    } else if (bid < 2864) {
        int gw = (bid - 816) * 4 + (t >> 6);
        int lane = t & 63;
        int b = gw >> 8;
        int s0 = starts[gw];
        const float* src = res_all + (size_t)(b * SS + s0) * HH + lane * 12;
        unsigned short* dst = slotA + (size_t)gw * 1536 + lane * 12;
#pragma unroll
        for (int c2 = 0; c2 < 3; c2++) {
            float4 v = *reinterpret_cast<const float4*>(&src[c2 * 4]);
            ushort4 o;
            o.x = f2bf(v.x); o.y = f2bf(v.y); o.z = f2bf(v.z); o.w = f2bf(v.w);
            *reinterpret_cast<ushort4*>(&dst[c2 * 4]) = o;
        }
    } else {
        __shared__ float sres[HH];
        int bb = bid - 2864;
        int lane = t & 63, wave = t >> 6;
        for (int i = t; i < HH; i += 256) sres[i] = res[bb * HH + i];
        __syncthreads();
        for (int o = wave; o < NINTENT; o += 4) {
            float s = 0.f;
            for (int i = lane; i < HH; i += 64) s += sres[i] * id_w[o * HH + i];
#pragma unroll
            for (int off = 32; off > 0; off >>= 1) s += __shfl_xor(s, off);
            if (lane == 0) out[bb * NINTENT + o] = s + id_b[o];
        }
    }
}

// ================= L2: weight GEMMs, K-split x8 =================
// [0,288):   G1: Ppart[ks] += hi.hi + lo.hi + hi.lo over k-slice (36 tiles x 8 ks)
// [288,336): G2: WRpart[ks] = Ws . WvT^T over k-slice (6 ntiles x 8 ks)
__global__ __launch_bounds__(256) void gemm_weights(
    const uint4* __restrict__ WkT_hi, const uint4* __restrict__ WkT_lo,
    const uint4* __restrict__ WqT_hi, const uint4* __restrict__ WqT_lo,
    const uint4* __restrict__ WvT, const uint4* __restrict__ Wcomb,
    float* __restrict__ Ppart,   // [8][768][768]
    float* __restrict__ WRpart)  // [8][128][768]
{
    __shared__ uint4 sA[512];
    __shared__ uint4 sB[512];
    int bid = blockIdx.x;
    int t = threadIdx.x;
    int lane = t & 63, wave = t >> 6;
    int wm = wave >> 1, wn = wave & 1;
    int l16 = lane & 15, lk = lane >> 4;
    int srow = lane >> 2, schk = lane & 3;

    uint4* sA0 = &sA[wave * 128];
    uint4* sA1 = &sA[wave * 128 + 64];
    uint4* sB0 = &sB[wave * 128];
    uint4* sB1 = &sB[wave * 128 + 64];

    f32x4 acc[4][4] = {};

    if (bid < 288) {
        int tile = bid >> 3, ks = bid & 7;
        int mt = tile / 6, nt = tile % 6;
        int kb = ks * 12;
#pragma unroll
        for (int p = 0; p < 3; p++) {
            const uint4* Ab = (p == 1) ? WkT_lo : WkT_hi;
            const uint4* Bb = (p == 2) ? WqT_lo : WqT_hi;
            const uint4* Ag0 = Ab + (size_t)(mt * 128 + wave * 32 + srow) * 96 + kb + schk;
            const uint4* Ag1 = Ag0 + (size_t)16 * 96;
            const uint4* Bg0 = Bb + (size_t)(nt * 128 + wave * 32 + srow) * 96 + kb + schk;
            const uint4* Bg1 = Bg0 + (size_t)16 * 96;
            for (int k0 = 0; k0 < 12; k0 += 4) {
                gload16(Ag0 + k0, sA0); gload16(Ag1 + k0, sA1);
                gload16(Bg0 + k0, sB0); gload16(Bg1 + k0, sB1);
                __syncthreads();
                bf16x8 af[4], bfr[4];
#pragma unroll
                for (int i = 0; i < 4; i++)
                    af[i] = *reinterpret_cast<const bf16x8*>(&sA[(wm * 64 + i * 16 + l16) * 4 + lk]);
#pragma unroll
                for (int j = 0; j < 4; j++)
                    bfr[j] = *reinterpret_cast<const bf16x8*>(&sB[(wn * 64 + j * 16 + l16) * 4 + lk]);
#pragma unroll
                for (int i = 0; i < 4; i++)
#pragma unroll
                    for (int j = 0; j < 4; j++)
                        acc[i][j] = MF(af[i], bfr[j], acc[i][j]);
                __syncthreads();
            }
        }
        float* dst = Ppart + (size_t)ks * 589824;
#pragma unroll
        for (int i = 0; i < 4; i++)
#pragma unroll
            for (int j = 0; j < 4; j++) {
                int col = nt * 128 + wn * 64 + j * 16 + l16;
#pragma unroll
                for (int q = 0; q < 4; q++) {
                    int row = mt * 128 + wm * 64 + i * 16 + lk * 4 + q;
                    dst[(size_t)row * HH + col] = acc[i][j][q];
                }
            }
    } else {
        int idx = bid - 288;
        int nt = idx >> 3, ks = idx & 7;
        int kb = ks * 12;
        const uint4* Ag0 = Wcomb + (size_t)(wave * 32 + srow) * 192 + kb + schk;
        const uint4* Ag1 = Ag0 + (size_t)16 * 192;
        const uint4* Bg0 = WvT + (size_t)(nt * 128 + wave * 32 + srow) * 96 + kb + schk;
        const uint4* Bg1 = Bg0 + (size_t)16 * 96;
        for (int k0 = 0; k0 < 12; k0 += 4) {
            gload16(Ag0 + k0, sA0); gload16(Ag1 + k0, sA1);
            gload16(Bg0 + k0, sB0); gload16(Bg1 + k0, sB1);
            __syncthreads();
            bf16x8 af[4], bfr[4];
#pragma unroll
            for (int i = 0; i < 4; i++)
                af[i] = *reinterpret_cast<const bf16x8*>(&sA[(wm * 64 + i * 16 + l16) * 4 + lk]);
#pragma unroll
            for (int j = 0; j < 4; j++)
                bfr[j] = *reinterpret_cast<const bf16x8*>(&sB[(wn * 64 + j * 16 + l16) * 4 + lk]);
#pragma unroll
            for (int i = 0; i < 4; i++)
#pragma unroll
                for (int j = 0; j < 4; j++)
                    acc[i][j] = MF(af[i], bfr[j], acc[i][j]);
            __syncthreads();
        }
        float* dst = WRpart + (size_t)ks * 98304;
#pragma unroll
        for (int i = 0; i < 4; i++)
#pragma unroll
            for (int j = 0; j < 4; j++) {
                int col = nt * 128 + wn * 64 + j * 16 + l16;
#pragma unroll
                for (int q = 0; q < 4; q++) {
                    int row = wm * 64 + i * 16 + lk * 4 + q;
                    dst[(size_t)row * HH + col] = acc[i][j][q];
                }
            }
    }
}

// ================= L3: reductions =================
// [0,576): Pb = bf16(sum_ks Ppart);  [576,672): WcombR = bf16(sum_ks WRpart)
// [672,675): u = sum u_part;  675: wsbv
__global__ __launch_bounds__(256) void psum_kernel(
    const float4* __restrict__ Ppart, ushort4* __restrict__ Pb,
    const float4* __restrict__ WRpart, unsigned short* __restrict__ Wcomb,
    const float* __restrict__ u_part, float* __restrict__ u,
    const float* __restrict__ wsbv_part, float* __restrict__ wsbv)
{
    int bid = blockIdx.x, t = threadIdx.x;
    if (bid < 576) {
        int i = bid * 256 + t;   // float4 idx, 147456 total
        float4 s = Ppart[i];
#pragma unroll
        for (int k = 1; k < 8; k++) {
            float4 v = Ppart[(size_t)k * 147456 + i];
            s.x += v.x; s.y += v.y; s.z += v.z; s.w += v.w;
        }
        ushort4 o;
        o.x = f2bf(s.x); o.y = f2bf(s.y); o.z = f2bf(s.z); o.w = f2bf(s.w);
        Pb[i] = o;
    } else if (bid < 672) {
        int q = (bid - 576) * 256 + t;   // 0..24575 over 128x768 (float4)
        float4 s = WRpart[q];
#pragma unroll
        for (int k = 1; k < 8; k++) {
            float4 v = WRpart[(size_t)k * 24576 + q];
            s.x += v.x; s.y += v.y; s.z += v.z; s.w += v.w;
        }
        int row = q / 192, colq = q % 192;
        ushort4 o;
        o.x = f2bf(s.x); o.y = f2bf(s.y); o.z = f2bf(s.z); o.w = f2bf(s.w);
        *reinterpret_cast<ushort4*>(&Wcomb[row * 1536 + 768 + colq * 4]) = o;
    } else if (bid < 675) {
        int c = (bid - 672) * 256 + t;
        float s = 0.f;
#pragma unroll
        for (int ty = 0; ty < 12; ty++) s += u_part[ty * HH + c];
        u[c] = s;
    } else if (t < 128) {
        wsbv[t] = wsbv_part[t] + wsbv_part[128 + t] + wsbv_part[256 + t];
    }
}

// ================= L4: qp = slotA_left . Pb^T + u (64x128 tiles, 768 blocks) =
__global__ __launch_bounds__(256) void gemm_qp(
    const uint4* __restrict__ A,   // slotA [8192][192]
    const uint4* __restrict__ Bm,  // Pb [768][96]
    const float* __restrict__ u,
    float* __restrict__ qp)        // [8192][768]
{
    __shared__ uint4 sA[256];   // 64 rows
    __shared__ uint4 sB[512];   // 128 rows

    int bid = blockIdx.x;
    bid = (bid & 7) * 96 + (bid >> 3);   // 768 = 8 x 96
    int mt = bid / 6, nt = bid % 6;

    int t = threadIdx.x;
    int lane = t & 63, wave = t >> 6;
    int wm = wave >> 1, wn = wave & 1;
    int l16 = lane & 15, lk = lane >> 4;
    int srow = lane >> 2, schk = lane & 3;

    const uint4* Ag  = A + (size_t)(mt * 64 + wave * 16 + srow) * 192 + schk;
    const uint4* Bg0 = Bm + (size_t)(nt * 128 + wave * 32 + srow) * 96 + schk;
    const uint4* Bg1 = Bg0 + (size_t)16 * 96;
    uint4* sAp = &sA[wave * 64];
    uint4* sB0 = &sB[wave * 128];
    uint4* sB1 = &sB[wave * 128 + 64];

    f32x4 acc[2][4] = {};

    for (int k0 = 0; k0 < 96; k0 += 4) {
        gload16(Ag + k0, sAp);
        gload16(Bg0 + k0, sB0);
        gload16(Bg1 + k0, sB1);
        __syncthreads();
        bf16x8 af[2], bfr[4];
#pragma unroll
        for (int i = 0; i < 2; i++)
            af[i] = *reinterpret_cast<const bf16x8*>(&sA[(wm * 32 + i * 16 + l16) * 4 + lk]);
#pragma unroll
        for (int j = 0; j < 4; j++)
            bfr[j] = *reinterpret_cast<const bf16x8*>(&sB[(wn * 64 + j * 16 + l16) * 4 + lk]);
#pragma unroll
        for (int i = 0; i < 2; i++)
#pragma unroll
            for (int j = 0; j < 4; j++)
                acc[i][j] = MF(af[i], bfr[j], acc[i][j]);
        __syncthreads();
    }

#pragma unroll
    for (int i = 0; i < 2; i++)
#pragma unroll
        for (int j = 0; j < 4; j++) {
            int col = nt * 128 + wn * 64 + j * 16 + l16;
            float add = u[col];
#pragma unroll
            for (int q = 0; q < 4; q++) {
                int row = mt * 64 + wm * 32 + i * 16 + lk * 4 + q;
                qp[(size_t)row * HH + col] = acc[i][j][q] + add;
            }
        }
}

// ================= L5: attention (scores f32, xbar -> slotA right) ==========
__global__ __launch_bounds__(256) void attn2_kernel(
    const float* __restrict__ qp,        // [8192][768] f32
    const float* __restrict__ res_all,   // [B*S][768] f32
    const int* __restrict__ starts,
    const int* __restrict__ lens,
    unsigned short* __restrict__ slotA)  // [8192][1536], writes cols 768..1535
{
    int bid = blockIdx.x;
    bid = (bid & 7) * 256 + (bid >> 3);              // 2048 = 8 x 256
    int gw = bid * 4 + (threadIdx.x >> 6);
    int lane = threadIdx.x & 63;
    int b = gw >> 8;
    int s0 = starts[gw];
    int sl = lens[gw];                               // 1..7, wave-uniform

    unsigned short* dst = slotA + (size_t)gw * 1536 + 768 + lane * 12;

    if (sl == 1) {                                   // word = first; xbar half = 0
        ushort4 z = {0, 0, 0, 0};
#pragma unroll
        for (int c = 0; c < 3; c++) *reinterpret_cast<ushort4*>(&dst[c * 4]) = z;
        return;
    }

    const float* qrow = qp + (size_t)gw * HH + lane * 12;
    float q[12];
#pragma unroll
    for (int c = 0; c < 3; c++) {
        float4 v = *reinterpret_cast<const float4*>(&qrow[c * 4]);
        q[c * 4 + 0] = v.x; q[c * 4 + 1] = v.y; q[c * 4 + 2] = v.z; q[c * 4 + 3] = v.w;
    }

    float scores[8];
#pragma unroll
    for (int k = 0; k < LL; k++) {
        if (k > sl) break;                           // uniform branch
        int s = s0 + k; if (s > SS - 1) s = SS - 1;
        const float* xr = res_all + (size_t)(b * SS + s) * HH + lane * 12;
        float partial = 0.f;
#pragma unroll
        for (int c = 0; c < 3; c++) {
            float4 v = *reinterpret_cast<const float4*>(&xr[c * 4]);
            partial += q[c * 4 + 0] * v.x + q[c * 4 + 1] * v.y
                     + q[c * 4 + 2] * v.z + q[c * 4 + 3] * v.w;
        }
#pragma unroll
        for (int off = 32; off > 0; off >>= 1) partial += __shfl_xor(partial, off);
        scores[k] = partial;
    }

    float m = -1e30f;
    for (int k = 0; k < LL; k++) if (k <= sl && scores[k] > m) m = scores[k];
    float p[8], ssum = 0.f;
    for (int k = 0; k < LL; k++) {
        p[k] = (k <= sl) ? __expf(scores[k] - m) : 0.f;
        ssum += p[k];
    }
    float inv = 1.f / ssum;

    float acc[12];
#pragma unroll
    for (int i = 0; i < 12; i++) acc[i] = 0.f;
    for (int k = 0; k < LL; k++) {
        if (k > sl) break;
        int s = s0 + k; if (s > SS - 1) s = SS - 1;
        const float* xr = res_all + (size_t)(b * SS + s) * HH + lane * 12;
        float wk = p[k] * inv;
#pragma unroll
        for (int c = 0; c < 3; c++) {
            float4 v = *reinterpret_cast<const float4*>(&xr[c * 4]);
            acc[c * 4 + 0] += wk * v.x; acc[c * 4 + 1] += wk * v.y;
            acc[c * 4 + 2] += wk * v.z; acc[c * 4 + 3] += wk * v.w;
        }
    }

#pragma unroll
    for (int c = 0; c < 3; c++) {
        ushort4 o;
        o.x = f2bf(acc[c * 4 + 0]); o.y = f2bf(acc[c * 4 + 1]);
        o.z = f2bf(acc[c * 4 + 2]); o.w = f2bf(acc[c * 4 + 3]);
        *reinterpret_cast<ushort4*>(&dst[c * 4]) = o;
    }
}

// ================= L6: slot GEMM, K-split x2 -> Cpart =================
__global__ __launch_bounds__(256) void gemm_slot3(
    const uint4* __restrict__ A,    // slotA [8192][192]
    const uint4* __restrict__ Bm,   // Wcomb [128][192]
    float* __restrict__ Cpart)      // [2][8192][128] f32
{
    __shared__ uint4 sA[256];   // 64 rows
    __shared__ uint4 sB[512];   // 128 rows

    int bid = blockIdx.x;
    int mt = bid >> 1, ks = bid & 1;
    int t = threadIdx.x;
    int lane = t & 63, wave = t >> 6;
    int wm = wave >> 1, wn = wave & 1;
    int l16 = lane & 15, lk = lane >> 4;
    int srow = lane >> 2, schk = lane & 3;

    const uint4* Ag  = A + (size_t)(mt * 64 + wave * 16 + srow) * 192 + ks * 96 + schk;
    const uint4* Bg0 = Bm + (size_t)(wave * 32 + srow) * 192 + ks * 96 + schk;
    const uint4* Bg1 = Bg0 + (size_t)16 * 192;
    uint4* sAp = &sA[wave * 64];
    uint4* sB0 = &sB[wave * 128];
    uint4* sB1 = &sB[wave * 128 + 64];

    f32x4 acc[2][4] = {};

    for (int k0 = 0; k0 < 96; k0 += 4) {
        gload16(Ag + k0, sAp);
        gload16(Bg0 + k0, sB0);
        gload16(Bg1 + k0, sB1);
        __syncthreads();
        bf16x8 af[2], bfr[4];
#pragma unroll
        for (int i = 0; i < 2; i++)
            af[i] = *reinterpret_cast<const bf16x8*>(&sA[(wm * 32 + i * 16 + l16) * 4 + lk]);
#pragma unroll
        for (int j = 0; j < 4; j++)
            bfr[j] = *reinterpret_cast<const bf16x8*>(&sB[(wn * 64 + j * 16 + l16) * 4 + lk]);
#pragma unroll
        for (int i = 0; i < 2; i++)
#pragma unroll
            for (int j = 0; j < 4; j++)
                acc[i][j] = MF(af[i], bfr[j], acc[i][j]);
        __syncthreads();
    }

    float* dst = Cpart + (size_t)ks * 1048576;
#pragma unroll
    for (int i = 0; i < 2; i++)
#pragma unroll
        for (int j = 0; j < 4; j++) {
            int col = wn * 64 + j * 16 + l16;
#pragma unroll
            for (int q = 0; q < 4; q++) {
                int row = mt * 64 + wm * 32 + i * 16 + lk * 4 + q;
                dst[(size_t)row * 128 + col] = acc[i][j][q];
            }
        }
}

// ================= L7: merge Cpart + bias + [sl>1]*wsbv -> out ==============
__global__ __launch_bounds__(256) void merge_kernel(
    const float* __restrict__ Cpart, const float* __restrict__ bias,
    const float* __restrict__ wsbv, const int* __restrict__ lens,
    float* __restrict__ outsf)
{
    int bid = blockIdx.x, t = threadIdx.x;
    int col = t & 127;
    if (col >= NSLOT) return;
    float bc = bias[col] ;
    float wv = wsbv[col];
#pragma unroll
    for (int j = 0; j < 2; j++) {
        int row = bid * 4 + (t >> 7) * 2 + j;
        float v = Cpart[(size_t)row * 128 + col]
                + Cpart[(size_t)1048576 + (size_t)row * 128 + col]
                + bc + ((lens[row] > 1) ? wv : 0.f);
        outsf[(size_t)row * NSLOT + col] = v;
    }
}

// ---------------- launch ----------------
extern "C" void kernel_launch(void* const* d_in, const int* in_sizes, int n_in,
                              void* d_out, int out_size, void* d_ws, size_t ws_size,
                              hipStream_t stream) {
    const float* res_all    = (const float*)d_in[0];
    const float* res        = (const float*)d_in[1];
    const int*   starts     = (const int*)d_in[2];
    const int*   lens       = (const int*)d_in[3];
    const float* Wsq_w      = (const float*)d_in[4];
    const float* Wsq_b      = (const float*)d_in[5];
    const float* Wsk_w      = (const float*)d_in[6];
    const float* Wsk_b      = (const float*)d_in[7];
    const float* Wsv_w      = (const float*)d_in[8];
    const float* Wsv_b      = (const float*)d_in[9];
    const float* lin_id_w   = (const float*)d_in[10];
    const float* lin_id_b   = (const float*)d_in[11];
    const float* lin_slot_w = (const float*)d_in[12];
    const float* lin_slot_b = (const float*)d_in[13];
    float* out = (float*)d_out;
    (void)Wsk_b;  // softmax-invariant (constant over k)

    char* ws = (char*)d_ws;
    unsigned short* slotA     = (unsigned short*)(ws + 0);          // 8192x1536 bf16
    float*          qp        = (float*)(ws + 25165824);            // 8192x768 f32
    unsigned short* WkT_hi    = (unsigned short*)(ws + 50331648);
    unsigned short* WkT_lo    = (unsigned short*)(ws + 51511296);
    unsigned short* WqT_hi    = (unsigned short*)(ws + 52690944);
    unsigned short* WqT_lo    = (unsigned short*)(ws + 53870592);
    unsigned short* WvT       = (unsigned short*)(ws + 55050240);
    unsigned short* Pb        = (unsigned short*)(ws + 56229888);   // 768^2 bf16
    unsigned short* Wcomb     = (unsigned short*)(ws + 57409536);   // 128x1536 bf16
    float*          u         = (float*)(ws + 57802752);            // 768
    float*          wsbv      = (float*)(ws + 57805824);            // 128
    float*          u_part    = (float*)(ws + 57806336);            // 12x768
    float*          wsbv_part = (float*)(ws + 57843200);            // 3x128
    float*          Ppart     = (float*)(ws + 57845760);            // 8x768x768 f32
    float*          WRpart    = (float*)(ws + 76720128);            // 8x128x768 f32
    float*          Cpart     = (float*)(ws + 79865856);            // 2x8192x128 f32

    // L1: mega prep
    prep_all<<<2896, 256, 0, stream>>>(
        Wsk_w, Wsq_w, Wsv_w, lin_slot_w, Wsq_b, Wsv_b,
        res_all, starts, res, lin_id_w, lin_id_b,
        WkT_hi, WkT_lo, WqT_hi, WqT_lo, WvT, Wcomb,
        u_part, wsbv_part, slotA, out);

    // L2: weight GEMMs (K-split x8)
    gemm_weights<<<336, 256, 0, stream>>>(
        (const uint4*)WkT_hi, (const uint4*)WkT_lo,
        (const uint4*)WqT_hi, (const uint4*)WqT_lo,
        (const uint4*)WvT, (const uint4*)Wcomb,
        Ppart, WRpart);

    // L3: reductions
    psum_kernel<<<676, 256, 0, stream>>>(
        (const float4*)Ppart, (ushort4*)Pb, (const float4*)WRpart, Wcomb,
        u_part, u, wsbv_part, wsbv);

    // L4: qp = slotA_left . Pb^T + u
    gemm_qp<<<768, 256, 0, stream>>>((const uint4*)slotA, (const uint4*)Pb, u, qp);

    // L5: attention -> slotA right half
    attn2_kernel<<<2048, 256, 0, stream>>>(qp, res_all, starts, lens, slotA);

    // L6: slot GEMM partials
    gemm_slot3<<<256, 256, 0, stream>>>((const uint4*)slotA, (const uint4*)Wcomb, Cpart);

    // L7: merge -> out
    merge_kernel<<<2048, 256, 0, stream>>>(Cpart, lin_slot_b, wsbv, lens, out + 832);
}

// Round 8
// 97.490 us; speedup vs baseline: 2.3641x; 1.2418x over previous
//
#include <hip/hip_runtime.h>
#include <cstdint>
#include <cstddef>

// Problem constants
#define BB 32
#define SS 512
#define HH 768
#define WW 256
#define LL 8
#define NINTENT 26
#define NSLOT 121

typedef float f32x4 __attribute__((ext_vector_type(4)));
typedef __bf16 bf16x8 __attribute__((ext_vector_type(8)));

static __device__ __forceinline__ float bf2f(unsigned short u) {
    union { unsigned int i; float f; } x; x.i = ((unsigned int)u) << 16; return x.f;
}
static __device__ __forceinline__ unsigned short f2bf(float f) {
    union { float f; unsigned int i; } x; x.f = f;
    unsigned int r = (x.i + 0x7fffu + ((x.i >> 16) & 1u)) >> 16;
    return (unsigned short)r;
}

// async global->LDS, 16B per lane, wave-uniform LDS base + lane*16
static __device__ __forceinline__ void gload16(const void* g, void* l) {
    __builtin_amdgcn_global_load_lds(
        (const __attribute__((address_space(1))) void*)g,
        (__attribute__((address_space(3))) void*)l, 16, 0, 0);
}

#define MF(a, b, c) __builtin_amdgcn_mfma_f32_16x16x32_bf16((a), (b), (c), 0, 0, 0)

// ================= K1: weight prep =================
// [0,432):   64x64 transpose + hi/lo split (Wk,Wq) / hi (Wv); Wk also u-partials
// [432,816): Wcomb left copy (bf16 Ws, zero pad) + wsbv partials
__global__ __launch_bounds__(256) void prep_w(
    const float* __restrict__ Wk, const float* __restrict__ Wq,
    const float* __restrict__ Wv, const float* __restrict__ Ws,
    const float* __restrict__ bq, const float* __restrict__ bv,
    unsigned short* __restrict__ WkT_hi, unsigned short* __restrict__ WkT_lo,
    unsigned short* __restrict__ WqT_hi, unsigned short* __restrict__ WqT_lo,
    unsigned short* __restrict__ WvT, unsigned short* __restrict__ Wcomb,
    float* __restrict__ u_part,     // [12][768]
    float* __restrict__ wsbv_part)  // [3][128]
{
    int bid = blockIdx.x;
    int t = threadIdx.x;

    if (bid < 432) {
        __shared__ float tl[64][65];
        int mb = bid / 144, tb = bid % 144;
        int tx = tb % 12, ty = tb / 12;
        const float* src = (mb == 0) ? Wk : (mb == 1) ? Wq : Wv;
        int rr = t >> 4, c4 = (t & 15) * 4;
#pragma unroll
        for (int j = 0; j < 4; j++) {
            float4 v = *reinterpret_cast<const float4*>(
                &src[(size_t)(ty * 64 + rr + 16 * j) * HH + tx * 64 + c4]);
            tl[rr + 16 * j][c4 + 0] = v.x; tl[rr + 16 * j][c4 + 1] = v.y;
            tl[rr + 16 * j][c4 + 2] = v.z; tl[rr + 16 * j][c4 + 3] = v.w;
        }
        __syncthreads();
        int il = t >> 4, o4 = (t & 15) * 4;
        unsigned short* dhi = (mb == 0) ? WkT_hi : (mb == 1) ? WqT_hi : WvT;
        unsigned short* dlo = (mb == 0) ? WkT_lo : WqT_lo;  // unused when mb==2
#pragma unroll
        for (int j = 0; j < 4; j++) {
            int i = il + 16 * j;
            float v0 = tl[o4 + 0][i], v1 = tl[o4 + 1][i];
            float v2 = tl[o4 + 2][i], v3 = tl[o4 + 3][i];
            size_t off = (size_t)(tx * 64 + i) * HH + ty * 64 + o4;
            ushort4 h;
            h.x = f2bf(v0); h.y = f2bf(v1); h.z = f2bf(v2); h.w = f2bf(v3);
            *reinterpret_cast<ushort4*>(&dhi[off]) = h;
            if (mb < 2) {
                ushort4 l;
                l.x = f2bf(v0 - bf2f(h.x)); l.y = f2bf(v1 - bf2f(h.y));
                l.z = f2bf(v2 - bf2f(h.z)); l.w = f2bf(v3 - bf2f(h.w));
                *reinterpret_cast<ushort4*>(&dlo[off]) = l;
            }
        }
        if (mb == 0) {  // u_part[ty][tx*64+c] = sum_r bq[ty*64+r]*Wk[ty*64+r][tx*64+c]
            int c = t >> 2, q = t & 3;
            float s = 0.f;
#pragma unroll
            for (int r = 0; r < 16; r++)
                s += bq[ty * 64 + q * 16 + r] * tl[q * 16 + r][c];
            s += __shfl_xor(s, 1);
            s += __shfl_xor(s, 2);
            if (q == 0) u_part[ty * HH + tx * 64 + c] = s;
        }
    } else {
        __shared__ float wred[4];
        int bid2 = bid - 432;
        int idx = bid2 * 256 + t;         // 0..98303 over 128x768
        int row = idx / HH, col = idx % HH;
        float v = (row < NSLOT) ? Ws[row * HH + col] : 0.f;
        Wcomb[row * 1536 + col] = f2bf(v);
        float pv = v * bv[col];
        int lane = t & 63, wave = t >> 6;
#pragma unroll
        for (int off = 32; off > 0; off >>= 1) pv += __shfl_xor(pv, off);
        if (lane == 0) wred[wave] = pv;
        __syncthreads();
        if (t == 0)
            wsbv_part[(bid2 % 3) * 128 + row] = wred[0] + wred[1] + wred[2] + wred[3];
    }
}

// ================= K2: weight GEMMs + gather + res_id =================
// [0,288):    G1: Ppart[ks] = hi.hi + lo.hi + hi.lo over k-slice
// [288,336):  G2: WRpart[ks] = Ws . WvT^T over k-slice
// [336,2384): gather first rows -> slotA left half
// [2384,2592): res_id, one wave per (bb, o)
__global__ __launch_bounds__(256) void gemm_weights(
    const uint4* __restrict__ WkT_hi, const uint4* __restrict__ WkT_lo,
    const uint4* __restrict__ WqT_hi, const uint4* __restrict__ WqT_lo,
    const uint4* __restrict__ WvT, const uint4* __restrict__ Wcomb,
    const float* __restrict__ res_all, const int* __restrict__ starts,
    const float* __restrict__ res, const float* __restrict__ id_w,
    const float* __restrict__ id_b,
    float* __restrict__ Ppart,   // [8][768][768]
    float* __restrict__ WRpart,  // [8][128][768]
    unsigned short* __restrict__ slotA,  // [8192][1536]
    float* __restrict__ out)
{
    __shared__ uint4 sA[512];
    __shared__ uint4 sB[512];
    int bid = blockIdx.x;
    int t = threadIdx.x;
    int lane = t & 63, wave = t >> 6;

    if (bid >= 2384) {           // ---- res_id: wave per (bb, o) ----
        int w = (bid - 2384) * 4 + wave;   // 0..831
        int bb = w / 26, o = w - bb * 26;
        const float* rrow = res + bb * HH + lane * 12;
        const float* wrow = id_w + o * HH + lane * 12;
        float s = 0.f;
#pragma unroll
        for (int c = 0; c < 3; c++) {
            float4 a = *reinterpret_cast<const float4*>(&rrow[c * 4]);
            float4 b = *reinterpret_cast<const float4*>(&wrow[c * 4]);
            s += a.x * b.x + a.y * b.y + a.z * b.z + a.w * b.w;
        }
#pragma unroll
        for (int off = 32; off > 0; off >>= 1) s += __shfl_xor(s, off);
        if (lane == 0) out[bb * NINTENT + o] = s + id_b[o];
        return;
    }
    if (bid >= 336) {            // ---- gather first rows ----
        int gw = (bid - 336) * 4 + wave;
        int b = gw >> 8;
        int s0 = starts[gw];
        const float* src = res_all + (size_t)(b * SS + s0) * HH + lane * 12;
        unsigned short* dst = slotA + (size_t)gw * 1536 + lane * 12;
#pragma unroll
        for (int c2 = 0; c2 < 3; c2++) {
            float4 v = *reinterpret_cast<const float4*>(&src[c2 * 4]);
            ushort4 o;
            o.x = f2bf(v.x); o.y = f2bf(v.y); o.z = f2bf(v.z); o.w = f2bf(v.w);
            *reinterpret_cast<ushort4*>(&dst[c2 * 4]) = o;
        }
        return;
    }

    int wm = wave >> 1, wn = wave & 1;
    int l16 = lane & 15, lk = lane >> 4;
    int srow = lane >> 2, schk = lane & 3;
    uint4* sA0 = &sA[wave * 128];
    uint4* sA1 = &sA[wave * 128 + 64];
    uint4* sB0 = &sB[wave * 128];
    uint4* sB1 = &sB[wave * 128 + 64];

    f32x4 acc[4][4] = {};

    if (bid < 288) {
        int tile = bid >> 3, ks = bid & 7;
        int mt = tile / 6, nt = tile % 6;
        int kb = ks * 12;
#pragma unroll
        for (int p = 0; p < 3; p++) {
            const uint4* Ab = (p == 1) ? WkT_lo : WkT_hi;
            const uint4* Bb = (p == 2) ? WqT_lo : WqT_hi;
            const uint4* Ag0 = Ab + (size_t)(mt * 128 + wave * 32 + srow) * 96 + kb + schk;
            const uint4* Ag1 = Ag0 + (size_t)16 * 96;
            const uint4* Bg0 = Bb + (size_t)(nt * 128 + wave * 32 + srow) * 96 + kb + schk;
            const uint4* Bg1 = Bg0 + (size_t)16 * 96;
            for (int k0 = 0; k0 < 12; k0 += 4) {
                gload16(Ag0 + k0, sA0); gload16(Ag1 + k0, sA1);
                gload16(Bg0 + k0, sB0); gload16(Bg1 + k0, sB1);
                __syncthreads();
                bf16x8 af[4], bfr[4];
#pragma unroll
                for (int i = 0; i < 4; i++)
                    af[i] = *reinterpret_cast<const bf16x8*>(&sA[(wm * 64 + i * 16 + l16) * 4 + lk]);
#pragma unroll
                for (int j = 0; j < 4; j++)
                    bfr[j] = *reinterpret_cast<const bf16x8*>(&sB[(wn * 64 + j * 16 + l16) * 4 + lk]);
#pragma unroll
                for (int i = 0; i < 4; i++)
#pragma unroll
                    for (int j = 0; j < 4; j++)
                        acc[i][j] = MF(af[i], bfr[j], acc[i][j]);
                __syncthreads();
            }
        }
        float* dst = Ppart + (size_t)ks * 589824;
#pragma unroll
        for (int i = 0; i < 4; i++)
#pragma unroll
            for (int j = 0; j < 4; j++) {
                int col = nt * 128 + wn * 64 + j * 16 + l16;
#pragma unroll
                for (int q = 0; q < 4; q++) {
                    int row = mt * 128 + wm * 64 + i * 16 + lk * 4 + q;
                    dst[(size_t)row * HH + col] = acc[i][j][q];
                }
            }
    } else {
        int idx = bid - 288;
        int nt = idx >> 3, ks = idx & 7;
        int kb = ks * 12;
        const uint4* Ag0 = Wcomb + (size_t)(wave * 32 + srow) * 192 + kb + schk;
        const uint4* Ag1 = Ag0 + (size_t)16 * 192;
        const uint4* Bg0 = WvT + (size_t)(nt * 128 + wave * 32 + srow) * 96 + kb + schk;
        const uint4* Bg1 = Bg0 + (size_t)16 * 96;
        for (int k0 = 0; k0 < 12; k0 += 4) {
            gload16(Ag0 + k0, sA0); gload16(Ag1 + k0, sA1);
            gload16(Bg0 + k0, sB0); gload16(Bg1 + k0, sB1);
            __syncthreads();
            bf16x8 af[4], bfr[4];
#pragma unroll
            for (int i = 0; i < 4; i++)
                af[i] = *reinterpret_cast<const bf16x8*>(&sA[(wm * 64 + i * 16 + l16) * 4 + lk]);
#pragma unroll
            for (int j = 0; j < 4; j++)
                bfr[j] = *reinterpret_cast<const bf16x8*>(&sB[(wn * 64 + j * 16 + l16) * 4 + lk]);
#pragma unroll
            for (int i = 0; i < 4; i++)
#pragma unroll
                for (int j = 0; j < 4; j++)
                    acc[i][j] = MF(af[i], bfr[j], acc[i][j]);
            __syncthreads();
        }
        float* dst = WRpart + (size_t)ks * 98304;
#pragma unroll
        for (int i = 0; i < 4; i++)
#pragma unroll
            for (int j = 0; j < 4; j++) {
                int col = nt * 128 + wn * 64 + j * 16 + l16;
#pragma unroll
                for (int q = 0; q < 4; q++) {
                    int row = wm * 64 + i * 16 + lk * 4 + q;
                    dst[(size_t)row * HH + col] = acc[i][j][q];
                }
            }
    }
}

// ================= K3: reductions =================
__global__ __launch_bounds__(256) void psum_kernel(
    const float4* __restrict__ Ppart, ushort4* __restrict__ Pb,
    const float4* __restrict__ WRpart, unsigned short* __restrict__ Wcomb,
    const float* __restrict__ u_part, float* __restrict__ u,
    const float* __restrict__ wsbv_part, float* __restrict__ wsbv)
{
    int bid = blockIdx.x, t = threadIdx.x;
    if (bid < 576) {
        int i = bid * 256 + t;   // float4 idx, 147456 total
        float4 s = Ppart[i];
#pragma unroll
        for (int k = 1; k < 8; k++) {
            float4 v = Ppart[(size_t)k * 147456 + i];
            s.x += v.x; s.y += v.y; s.z += v.z; s.w += v.w;
        }
        ushort4 o;
        o.x = f2bf(s.x); o.y = f2bf(s.y); o.z = f2bf(s.z); o.w = f2bf(s.w);
        Pb[i] = o;
    } else if (bid < 672) {
        int q = (bid - 576) * 256 + t;   // 0..24575 over 128x768 (float4)
        float4 s = WRpart[q];
#pragma unroll
        for (int k = 1; k < 8; k++) {
            float4 v = WRpart[(size_t)k * 24576 + q];
            s.x += v.x; s.y += v.y; s.z += v.z; s.w += v.w;
        }
        int row = q / 192, colq = q % 192;
        ushort4 o;
        o.x = f2bf(s.x); o.y = f2bf(s.y); o.z = f2bf(s.z); o.w = f2bf(s.w);
        *reinterpret_cast<ushort4*>(&Wcomb[row * 1536 + 768 + colq * 4]) = o;
    } else if (bid < 675) {
        int c = (bid - 672) * 256 + t;
        float s = 0.f;
#pragma unroll
        for (int ty = 0; ty < 12; ty++) s += u_part[ty * HH + c];
        u[c] = s;
    } else if (t < 128) {
        wsbv[t] = wsbv_part[t] + wsbv_part[128 + t] + wsbv_part[256 + t];
    }
}

// ================= K4: qp = slotA_left . Pb^T + u (64x128 tiles) =================
__global__ __launch_bounds__(256) void gemm_qp(
    const uint4* __restrict__ A,   // slotA [8192][192]
    const uint4* __restrict__ Bm,  // Pb [768][96]
    const float* __restrict__ u,
    float* __restrict__ qp)        // [8192][768]
{
    __shared__ uint4 sA[256];   // 64 rows
    __shared__ uint4 sB[512];   // 128 rows

    int bid = blockIdx.x;
    bid = (bid & 7) * 96 + (bid >> 3);   // 768 = 8 x 96
    int mt = bid / 6, nt = bid % 6;

    int t = threadIdx.x;
    int lane = t & 63, wave = t >> 6;
    int wm = wave >> 1, wn = wave & 1;
    int l16 = lane & 15, lk = lane >> 4;
    int srow = lane >> 2, schk = lane & 3;

    const uint4* Ag  = A + (size_t)(mt * 64 + wave * 16 + srow) * 192 + schk;
    const uint4* Bg0 = Bm + (size_t)(nt * 128 + wave * 32 + srow) * 96 + schk;
    const uint4* Bg1 = Bg0 + (size_t)16 * 96;
    uint4* sAp = &sA[wave * 64];
    uint4* sB0 = &sB[wave * 128];
    uint4* sB1 = &sB[wave * 128 + 64];

    f32x4 acc[2][4] = {};

    for (int k0 = 0; k0 < 96; k0 += 4) {
        gload16(Ag + k0, sAp);
        gload16(Bg0 + k0, sB0);
        gload16(Bg1 + k0, sB1);
        __syncthreads();
        bf16x8 af[2], bfr[4];
#pragma unroll
        for (int i = 0; i < 2; i++)
            af[i] = *reinterpret_cast<const bf16x8*>(&sA[(wm * 32 + i * 16 + l16) * 4 + lk]);
#pragma unroll
        for (int j = 0; j < 4; j++)
            bfr[j] = *reinterpret_cast<const bf16x8*>(&sB[(wn * 64 + j * 16 + l16) * 4 + lk]);
#pragma unroll
        for (int i = 0; i < 2; i++)
#pragma unroll
            for (int j = 0; j < 4; j++)
                acc[i][j] = MF(af[i], bfr[j], acc[i][j]);
        __syncthreads();
    }

#pragma unroll
    for (int i = 0; i < 2; i++)
#pragma unroll
        for (int j = 0; j < 4; j++) {
            int col = nt * 128 + wn * 64 + j * 16 + l16;
            float add = u[col];
#pragma unroll
            for (int q = 0; q < 4; q++) {
                int row = mt * 64 + wm * 32 + i * 16 + lk * 4 + q;
                qp[(size_t)row * HH + col] = acc[i][j][q] + add;
            }
        }
}

// ================= K5: attention (scores f32, xbar -> slotA right) ==========
__global__ __launch_bounds__(256) void attn2_kernel(
    const float* __restrict__ qp,        // [8192][768] f32
    const float* __restrict__ res_all,   // [B*S][768] f32
    const int* __restrict__ starts,
    const int* __restrict__ lens,
    unsigned short* __restrict__ slotA)  // [8192][1536], writes cols 768..1535
{
    int bid = blockIdx.x;
    bid = (bid & 7) * 256 + (bid >> 3);              // 2048 = 8 x 256
    int gw = bid * 4 + (threadIdx.x >> 6);
    int lane = threadIdx.x & 63;
    int b = gw >> 8;
    int s0 = starts[gw];
    int sl = lens[gw];                               // 1..7, wave-uniform

    unsigned short* dst = slotA + (size_t)gw * 1536 + 768 + lane * 12;

    if (sl == 1) {                                   // word = first; xbar half = 0
        ushort4 z = {0, 0, 0, 0};
#pragma unroll
        for (int c = 0; c < 3; c++) *reinterpret_cast<ushort4*>(&dst[c * 4]) = z;
        return;
    }

    const float* qrow = qp + (size_t)gw * HH + lane * 12;
    float q[12];
#pragma unroll
    for (int c = 0; c < 3; c++) {
        float4 v = *reinterpret_cast<const float4*>(&qrow[c * 4]);
        q[c * 4 + 0] = v.x; q[c * 4 + 1] = v.y; q[c * 4 + 2] = v.z; q[c * 4 + 3] = v.w;
    }

    float scores[8];
#pragma unroll
    for (int k = 0; k < LL; k++) {
        if (k > sl) break;                           // uniform branch
        int s = s0 + k; if (s > SS - 1) s = SS - 1;
        const float* xr = res_all + (size_t)(b * SS + s) * HH + lane * 12;
        float partial = 0.f;
#pragma unroll
        for (int c = 0; c < 3; c++) {
            float4 v = *reinterpret_cast<const float4*>(&xr[c * 4]);
            partial += q[c * 4 + 0] * v.x + q[c * 4 + 1] * v.y
                     + q[c * 4 + 2] * v.z + q[c * 4 + 3] * v.w;
        }
#pragma unroll
        for (int off = 32; off > 0; off >>= 1) partial += __shfl_xor(partial, off);
        scores[k] = partial;
    }

    float m = -1e30f;
    for (int k = 0; k < LL; k++) if (k <= sl && scores[k] > m) m = scores[k];
    float p[8], ssum = 0.f;
    for (int k = 0; k < LL; k++) {
        p[k] = (k <= sl) ? __expf(scores[k] - m) : 0.f;
        ssum += p[k];
    }
    float inv = 1.f / ssum;

    float acc[12];
#pragma unroll
    for (int i = 0; i < 12; i++) acc[i] = 0.f;
    for (int k = 0; k < LL; k++) {
        if (k > sl) break;
        int s = s0 + k; if (s > SS - 1) s = SS - 1;
        const float* xr = res_all + (size_t)(b * SS + s) * HH + lane * 12;
        float wk = p[k] * inv;
#pragma unroll
        for (int c = 0; c < 3; c++) {
            float4 v = *reinterpret_cast<const float4*>(&xr[c * 4]);
            acc[c * 4 + 0] += wk * v.x; acc[c * 4 + 1] += wk * v.y;
            acc[c * 4 + 2] += wk * v.z; acc[c * 4 + 3] += wk * v.w;
        }
    }

#pragma unroll
    for (int c = 0; c < 3; c++) {
        ushort4 o;
        o.x = f2bf(acc[c * 4 + 0]); o.y = f2bf(acc[c * 4 + 1]);
        o.z = f2bf(acc[c * 4 + 2]); o.w = f2bf(acc[c * 4 + 3]);
        *reinterpret_cast<ushort4*>(&dst[c * 4]) = o;
    }
}

// ================= K6: slot GEMM, K-split x2 -> Cpart =================
__global__ __launch_bounds__(256) void gemm_slot3(
    const uint4* __restrict__ A,    // slotA [8192][192]
    const uint4* __restrict__ Bm,   // Wcomb [128][192]
    float* __restrict__ Cpart)      // [2][8192][128] f32
{
    __shared__ uint4 sA[256];   // 64 rows
    __shared__ uint4 sB[512];   // 128 rows

    int bid = blockIdx.x;
    int mt = bid >> 1, ks = bid & 1;
    int t = threadIdx.x;
    int lane = t & 63, wave = t >> 6;
    int wm = wave >> 1, wn = wave & 1;
    int l16 = lane & 15, lk = lane >> 4;
    int srow = lane >> 2, schk = lane & 3;

    const uint4* Ag  = A + (size_t)(mt * 64 + wave * 16 + srow) * 192 + ks * 96 + schk;
    const uint4* Bg0 = Bm + (size_t)(wave * 32 + srow) * 192 + ks * 96 + schk;
    const uint4* Bg1 = Bg0 + (size_t)16 * 192;
    uint4* sAp = &sA[wave * 64];
    uint4* sB0 = &sB[wave * 128];
    uint4* sB1 = &sB[wave * 128 + 64];

    f32x4 acc[2][4] = {};

    for (int k0 = 0; k0 < 96; k0 += 4) {
        gload16(Ag + k0, sAp);
        gload16(Bg0 + k0, sB0);
        gload16(Bg1 + k0, sB1);
        __syncthreads();
        bf16x8 af[2], bfr[4];
#pragma unroll
        for (int i = 0; i < 2; i++)
            af[i] = *reinterpret_cast<const bf16x8*>(&sA[(wm * 32 + i * 16 + l16) * 4 + lk]);
#pragma unroll
        for (int j = 0; j < 4; j++)
            bfr[j] = *reinterpret_cast<const bf16x8*>(&sB[(wn * 64 + j * 16 + l16) * 4 + lk]);
#pragma unroll
        for (int i = 0; i < 2; i++)
#pragma unroll
            for (int j = 0; j < 4; j++)
                acc[i][j] = MF(af[i], bfr[j], acc[i][j]);
        __syncthreads();
    }

    float* dst = Cpart + (size_t)ks * 1048576;
#pragma unroll
    for (int i = 0; i < 2; i++)
#pragma unroll
        for (int j = 0; j < 4; j++) {
            int col = wn * 64 + j * 16 + l16;
#pragma unroll
            for (int q = 0; q < 4; q++) {
                int row = mt * 64 + wm * 32 + i * 16 + lk * 4 + q;
                dst[(size_t)row * 128 + col] = acc[i][j][q];
            }
        }
}

// ================= K7: merge Cpart + bias + [sl>1]*wsbv -> out ==============
__global__ __launch_bounds__(256) void merge_kernel(
    const float* __restrict__ Cpart, const float* __restrict__ bias,
    const float* __restrict__ wsbv, const int* __restrict__ lens,
    float* __restrict__ outsf)
{
    int bid = blockIdx.x, t = threadIdx.x;
    int col = t & 127;
    if (col >= NSLOT) return;
    float bc = bias[col];
    float wv = wsbv[col];
#pragma unroll
    for (int j = 0; j < 2; j++) {
        int row = bid * 4 + (t >> 7) * 2 + j;
        float v = Cpart[(size_t)row * 128 + col]
                + Cpart[(size_t)1048576 + (size_t)row * 128 + col]
                + bc + ((lens[row] > 1) ? wv : 0.f);
        outsf[(size_t)row * NSLOT + col] = v;
    }
}

// ---------------- launch ----------------
extern "C" void kernel_launch(void* const* d_in, const int* in_sizes, int n_in,
                              void* d_out, int out_size, void* d_ws, size_t ws_size,
                              hipStream_t stream) {
    const float* res_all    = (const float*)d_in[0];
    const float* res        = (const float*)d_in[1];
    const int*   starts     = (const int*)d_in[2];
    const int*   lens       = (const int*)d_in[3];
    const float* Wsq_w      = (const float*)d_in[4];
    const float* Wsq_b      = (const float*)d_in[5];
    const float* Wsk_w      = (const float*)d_in[6];
    const float* Wsk_b      = (const float*)d_in[7];
    const float* Wsv_w      = (const float*)d_in[8];
    const float* Wsv_b      = (const float*)d_in[9];
    const float* lin_id_w   = (const float*)d_in[10];
    const float* lin_id_b   = (const float*)d_in[11];
    const float* lin_slot_w = (const float*)d_in[12];
    const float* lin_slot_b = (const float*)d_in[13];
    float* out = (float*)d_out;
    (void)Wsk_b;  // softmax-invariant (constant over k)

    char* ws = (char*)d_ws;
    unsigned short* slotA     = (unsigned short*)(ws + 0);          // 8192x1536 bf16
    float*          qp        = (float*)(ws + 25165824);            // 8192x768 f32
    unsigned short* WkT_hi    = (unsigned short*)(ws + 50331648);
    unsigned short* WkT_lo    = (unsigned short*)(ws + 51511296);
    unsigned short* WqT_hi    = (unsigned short*)(ws + 52690944);
    unsigned short* WqT_lo    = (unsigned short*)(ws + 53870592);
    unsigned short* WvT       = (unsigned short*)(ws + 55050240);
    unsigned short* Pb        = (unsigned short*)(ws + 56229888);   // 768^2 bf16
    unsigned short* Wcomb     = (unsigned short*)(ws + 57409536);   // 128x1536 bf16
    float*          u         = (float*)(ws + 57802752);            // 768
    float*          wsbv      = (float*)(ws + 57805824);            // 128
    float*          u_part    = (float*)(ws + 57806336);            // 12x768
    float*          wsbv_part = (float*)(ws + 57843200);            // 3x128
    float*          Ppart     = (float*)(ws + 57845760);            // 8x768x768 f32
    float*          WRpart    = (float*)(ws + 76720128);            // 8x128x768 f32
    float*          Cpart     = (float*)(ws + 79865856);            // 2x8192x128 f32

    // K1: weight prep (transpose/split + Wcomb left)
    prep_w<<<816, 256, 0, stream>>>(
        Wsk_w, Wsq_w, Wsv_w, lin_slot_w, Wsq_b, Wsv_b,
        WkT_hi, WkT_lo, WqT_hi, WqT_lo, WvT, Wcomb,
        u_part, wsbv_part);

    // K2: weight GEMMs + gather + res_id
    gemm_weights<<<2592, 256, 0, stream>>>(
        (const uint4*)WkT_hi, (const uint4*)WkT_lo,
        (const uint4*)WqT_hi, (const uint4*)WqT_lo,
        (const uint4*)WvT, (const uint4*)Wcomb,
        res_all, starts, res, lin_id_w, lin_id_b,
        Ppart, WRpart, slotA, out);

    // K3: reductions
    psum_kernel<<<676, 256, 0, stream>>>(
        (const float4*)Ppart, (ushort4*)Pb, (const float4*)WRpart, Wcomb,
        u_part, u, wsbv_part, wsbv);

    // K4: qp = slotA_left . Pb^T + u
    gemm_qp<<<768, 256, 0, stream>>>((const uint4*)slotA, (const uint4*)Pb, u, qp);

    // K5: attention -> slotA right half
    attn2_kernel<<<2048, 256, 0, stream>>>(qp, res_all, starts, lens, slotA);

    // K6: slot GEMM partials
    gemm_slot3<<<256, 256, 0, stream>>>((const uint4*)slotA, (const uint4*)Wcomb, Cpart);

    // K7: merge -> out
    merge_kernel<<<2048, 256, 0, stream>>>(Cpart, lin_slot_b, wsbv, lens, out + 832);
}

// Round 9
// 88.314 us; speedup vs baseline: 2.6097x; 1.1039x over previous
//
#include <hip/hip_runtime.h>
#include <cstdint>
#include <cstddef>

// Problem constants
#define BB 32
#define SS 512
#define HH 768
#define WW 256
#define LL 8
#define NINTENT 26
#define NSLOT 121

typedef float f32x4 __attribute__((ext_vector_type(4)));
typedef __bf16 bf16x8 __attribute__((ext_vector_type(8)));

static __device__ __forceinline__ float bf2f(unsigned short u) {
    union { unsigned int i; float f; } x; x.i = ((unsigned int)u) << 16; return x.f;
}
static __device__ __forceinline__ unsigned short f2bf(float f) {
    union { float f; unsigned int i; } x; x.f = f;
    unsigned int r = (x.i + 0x7fffu + ((x.i >> 16) & 1u)) >> 16;
    return (unsigned short)r;
}

// async global->LDS, 16B per lane, wave-uniform LDS base + lane*16
static __device__ __forceinline__ void gload16(const void* g, void* l) {
    __builtin_amdgcn_global_load_lds(
        (const __attribute__((address_space(1))) void*)g,
        (__attribute__((address_space(3))) void*)l, 16, 0, 0);
}

#define MF(a, b, c) __builtin_amdgcn_mfma_f32_16x16x32_bf16((a), (b), (c), 0, 0, 0)

// ================= K1: weight prep =================
// [0,432):   64x64 transpose + hi/lo split (Wk,Wq) / hi (Wv); Wk also u-partials
// [432,816): Wcomb left copy (bf16 Ws, zero pad) + wsbv partials
__global__ __launch_bounds__(256) void prep_w(
    const float* __restrict__ Wk, const float* __restrict__ Wq,
    const float* __restrict__ Wv, const float* __restrict__ Ws,
    const float* __restrict__ bq, const float* __restrict__ bv,
    unsigned short* __restrict__ WkT_hi, unsigned short* __restrict__ WkT_lo,
    unsigned short* __restrict__ WqT_hi, unsigned short* __restrict__ WqT_lo,
    unsigned short* __restrict__ WvT, unsigned short* __restrict__ Wcomb,
    float* __restrict__ u_part,     // [12][768]
    float* __restrict__ wsbv_part)  // [3][128]
{
    int bid = blockIdx.x;
    int t = threadIdx.x;

    if (bid < 432) {
        __shared__ float tl[64][65];
        int mb = bid / 144, tb = bid % 144;
        int tx = tb % 12, ty = tb / 12;
        const float* src = (mb == 0) ? Wk : (mb == 1) ? Wq : Wv;
        int rr = t >> 4, c4 = (t & 15) * 4;
#pragma unroll
        for (int j = 0; j < 4; j++) {
            float4 v = *reinterpret_cast<const float4*>(
                &src[(size_t)(ty * 64 + rr + 16 * j) * HH + tx * 64 + c4]);
            tl[rr + 16 * j][c4 + 0] = v.x; tl[rr + 16 * j][c4 + 1] = v.y;
            tl[rr + 16 * j][c4 + 2] = v.z; tl[rr + 16 * j][c4 + 3] = v.w;
        }
        __syncthreads();
        int il = t >> 4, o4 = (t & 15) * 4;
        unsigned short* dhi = (mb == 0) ? WkT_hi : (mb == 1) ? WqT_hi : WvT;
        unsigned short* dlo = (mb == 0) ? WkT_lo : WqT_lo;  // unused when mb==2
#pragma unroll
        for (int j = 0; j < 4; j++) {
            int i = il + 16 * j;
            float v0 = tl[o4 + 0][i], v1 = tl[o4 + 1][i];
            float v2 = tl[o4 + 2][i], v3 = tl[o4 + 3][i];
            size_t off = (size_t)(tx * 64 + i) * HH + ty * 64 + o4;
            ushort4 h;
            h.x = f2bf(v0); h.y = f2bf(v1); h.z = f2bf(v2); h.w = f2bf(v3);
            *reinterpret_cast<ushort4*>(&dhi[off]) = h;
            if (mb < 2) {
                ushort4 l;
                l.x = f2bf(v0 - bf2f(h.x)); l.y = f2bf(v1 - bf2f(h.y));
                l.z = f2bf(v2 - bf2f(h.z)); l.w = f2bf(v3 - bf2f(h.w));
                *reinterpret_cast<ushort4*>(&dlo[off]) = l;
            }
        }
        if (mb == 0) {
            int c = t >> 2, q = t & 3;
            float s = 0.f;
#pragma unroll
            for (int r = 0; r < 16; r++)
                s += bq[ty * 64 + q * 16 + r] * tl[q * 16 + r][c];
            s += __shfl_xor(s, 1);
            s += __shfl_xor(s, 2);
            if (q == 0) u_part[ty * HH + tx * 64 + c] = s;
        }
    } else {
        __shared__ float wred[4];
        int bid2 = bid - 432;
        int idx = bid2 * 256 + t;         // 0..98303 over 128x768
        int row = idx / HH, col = idx % HH;
        float v = (row < NSLOT) ? Ws[row * HH + col] : 0.f;
        Wcomb[row * 1536 + col] = f2bf(v);
        float pv = v * bv[col];
        int lane = t & 63, wave = t >> 6;
#pragma unroll
        for (int off = 32; off > 0; off >>= 1) pv += __shfl_xor(pv, off);
        if (lane == 0) wred[wave] = pv;
        __syncthreads();
        if (t == 0)
            wsbv_part[(bid2 % 3) * 128 + row] = wred[0] + wred[1] + wred[2] + wred[3];
    }
}

// ================= K2: weight GEMMs + gather + res_id =================
__global__ __launch_bounds__(256) void gemm_weights(
    const uint4* __restrict__ WkT_hi, const uint4* __restrict__ WkT_lo,
    const uint4* __restrict__ WqT_hi, const uint4* __restrict__ WqT_lo,
    const uint4* __restrict__ WvT, const uint4* __restrict__ Wcomb,
    const float* __restrict__ res_all, const int* __restrict__ starts,
    const float* __restrict__ res, const float* __restrict__ id_w,
    const float* __restrict__ id_b,
    float* __restrict__ Ppart,   // [8][768][768]
    float* __restrict__ WRpart,  // [8][128][768]
    unsigned short* __restrict__ slotA,  // [8192][1536]
    float* __restrict__ out)
{
    __shared__ uint4 sA[512];
    __shared__ uint4 sB[512];
    int bid = blockIdx.x;
    int t = threadIdx.x;
    int lane = t & 63, wave = t >> 6;

    if (bid >= 2384) {           // ---- res_id: wave per (bb, o) ----
        int w = (bid - 2384) * 4 + wave;   // 0..831
        int bb = w / 26, o = w - bb * 26;
        const float* rrow = res + bb * HH + lane * 12;
        const float* wrow = id_w + o * HH + lane * 12;
        float s = 0.f;
#pragma unroll
        for (int c = 0; c < 3; c++) {
            float4 a = *reinterpret_cast<const float4*>(&rrow[c * 4]);
            float4 b = *reinterpret_cast<const float4*>(&wrow[c * 4]);
            s += a.x * b.x + a.y * b.y + a.z * b.z + a.w * b.w;
        }
#pragma unroll
        for (int off = 32; off > 0; off >>= 1) s += __shfl_xor(s, off);
        if (lane == 0) out[bb * NINTENT + o] = s + id_b[o];
        return;
    }
    if (bid >= 336) {            // ---- gather first rows ----
        int gw = (bid - 336) * 4 + wave;
        int b = gw >> 8;
        int s0 = starts[gw];
        const float* src = res_all + (size_t)(b * SS + s0) * HH + lane * 12;
        unsigned short* dst = slotA + (size_t)gw * 1536 + lane * 12;
#pragma unroll
        for (int c2 = 0; c2 < 3; c2++) {
            float4 v = *reinterpret_cast<const float4*>(&src[c2 * 4]);
            ushort4 o;
            o.x = f2bf(v.x); o.y = f2bf(v.y); o.z = f2bf(v.z); o.w = f2bf(v.w);
            *reinterpret_cast<ushort4*>(&dst[c2 * 4]) = o;
        }
        return;
    }

    int wm = wave >> 1, wn = wave & 1;
    int l16 = lane & 15, lk = lane >> 4;
    int srow = lane >> 2, schk = lane & 3;
    uint4* sA0 = &sA[wave * 128];
    uint4* sA1 = &sA[wave * 128 + 64];
    uint4* sB0 = &sB[wave * 128];
    uint4* sB1 = &sB[wave * 128 + 64];

    f32x4 acc[4][4] = {};

    if (bid < 288) {
        int tile = bid >> 3, ks = bid & 7;
        int mt = tile / 6, nt = tile % 6;
        int kb = ks * 12;
#pragma unroll
        for (int p = 0; p < 3; p++) {
            const uint4* Ab = (p == 1) ? WkT_lo : WkT_hi;
            const uint4* Bb = (p == 2) ? WqT_lo : WqT_hi;
            const uint4* Ag0 = Ab + (size_t)(mt * 128 + wave * 32 + srow) * 96 + kb + schk;
            const uint4* Ag1 = Ag0 + (size_t)16 * 96;
            const uint4* Bg0 = Bb + (size_t)(nt * 128 + wave * 32 + srow) * 96 + kb + schk;
            const uint4* Bg1 = Bg0 + (size_t)16 * 96;
            for (int k0 = 0; k0 < 12; k0 += 4) {
                gload16(Ag0 + k0, sA0); gload16(Ag1 + k0, sA1);
                gload16(Bg0 + k0, sB0); gload16(Bg1 + k0, sB1);
                __syncthreads();
                bf16x8 af[4], bfr[4];
#pragma unroll
                for (int i = 0; i < 4; i++)
                    af[i] = *reinterpret_cast<const bf16x8*>(&sA[(wm * 64 + i * 16 + l16) * 4 + lk]);
#pragma unroll
                for (int j = 0; j < 4; j++)
                    bfr[j] = *reinterpret_cast<const bf16x8*>(&sB[(wn * 64 + j * 16 + l16) * 4 + lk]);
#pragma unroll
                for (int i = 0; i < 4; i++)
#pragma unroll
                    for (int j = 0; j < 4; j++)
                        acc[i][j] = MF(af[i], bfr[j], acc[i][j]);
                __syncthreads();
            }
        }
        float* dst = Ppart + (size_t)ks * 589824;
#pragma unroll
        for (int i = 0; i < 4; i++)
#pragma unroll
            for (int j = 0; j < 4; j++) {
                int col = nt * 128 + wn * 64 + j * 16 + l16;
#pragma unroll
                for (int q = 0; q < 4; q++) {
                    int row = mt * 128 + wm * 64 + i * 16 + lk * 4 + q;
                    dst[(size_t)row * HH + col] = acc[i][j][q];
                }
            }
    } else {
        int idx = bid - 288;
        int nt = idx >> 3, ks = idx & 7;
        int kb = ks * 12;
        const uint4* Ag0 = Wcomb + (size_t)(wave * 32 + srow) * 192 + kb + schk;
        const uint4* Ag1 = Ag0 + (size_t)16 * 192;
        const uint4* Bg0 = WvT + (size_t)(nt * 128 + wave * 32 + srow) * 96 + kb + schk;
        const uint4* Bg1 = Bg0 + (size_t)16 * 96;
        for (int k0 = 0; k0 < 12; k0 += 4) {
            gload16(Ag0 + k0, sA0); gload16(Ag1 + k0, sA1);
            gload16(Bg0 + k0, sB0); gload16(Bg1 + k0, sB1);
            __syncthreads();
            bf16x8 af[4], bfr[4];
#pragma unroll
            for (int i = 0; i < 4; i++)
                af[i] = *reinterpret_cast<const bf16x8*>(&sA[(wm * 64 + i * 16 + l16) * 4 + lk]);
#pragma unroll
            for (int j = 0; j < 4; j++)
                bfr[j] = *reinterpret_cast<const bf16x8*>(&sB[(wn * 64 + j * 16 + l16) * 4 + lk]);
#pragma unroll
            for (int i = 0; i < 4; i++)
#pragma unroll
                for (int j = 0; j < 4; j++)
                    acc[i][j] = MF(af[i], bfr[j], acc[i][j]);
            __syncthreads();
        }
        float* dst = WRpart + (size_t)ks * 98304;
#pragma unroll
        for (int i = 0; i < 4; i++)
#pragma unroll
            for (int j = 0; j < 4; j++) {
                int col = nt * 128 + wn * 64 + j * 16 + l16;
#pragma unroll
                for (int q = 0; q < 4; q++) {
                    int row = wm * 64 + i * 16 + lk * 4 + q;
                    dst[(size_t)row * HH + col] = acc[i][j][q];
                }
            }
    }
}

// ================= K3: reductions =================
__global__ __launch_bounds__(256) void psum_kernel(
    const float4* __restrict__ Ppart, ushort4* __restrict__ Pb,
    const float4* __restrict__ WRpart, unsigned short* __restrict__ Wcomb,
    const float* __restrict__ u_part, float* __restrict__ u,
    const float* __restrict__ wsbv_part, float* __restrict__ wsbv)
{
    int bid = blockIdx.x, t = threadIdx.x;
    if (bid < 576) {
        int i = bid * 256 + t;   // float4 idx, 147456 total
        float4 s = Ppart[i];
#pragma unroll
        for (int k = 1; k < 8; k++) {
            float4 v = Ppart[(size_t)k * 147456 + i];
            s.x += v.x; s.y += v.y; s.z += v.z; s.w += v.w;
        }
        ushort4 o;
        o.x = f2bf(s.x); o.y = f2bf(s.y); o.z = f2bf(s.z); o.w = f2bf(s.w);
        Pb[i] = o;
    } else if (bid < 672) {
        int q = (bid - 576) * 256 + t;   // 0..24575 over 128x768 (float4)
        float4 s = WRpart[q];
#pragma unroll
        for (int k = 1; k < 8; k++) {
            float4 v = WRpart[(size_t)k * 24576 + q];
            s.x += v.x; s.y += v.y; s.z += v.z; s.w += v.w;
        }
        int row = q / 192, colq = q % 192;
        ushort4 o;
        o.x = f2bf(s.x); o.y = f2bf(s.y); o.z = f2bf(s.z); o.w = f2bf(s.w);
        *reinterpret_cast<ushort4*>(&Wcomb[row * 1536 + 768 + colq * 4]) = o;
    } else if (bid < 675) {
        int c = (bid - 672) * 256 + t;
        float s = 0.f;
#pragma unroll
        for (int ty = 0; ty < 12; ty++) s += u_part[ty * HH + c];
        u[c] = s;
    } else if (t < 128) {
        wsbv[t] = wsbv_part[t] + wsbv_part[128 + t] + wsbv_part[256 + t];
    }
}

// ================= K4': qp GEMM (768 blocks) + slot-left GEMM (256 blocks) ===
// [0,768):    qp = slotA_left . Pb^T + u  (64x128 tiles, f32 out)
// [768,1024): Cpart0 = slotA_left . WcombL^T  (32x128 tiles, f32 out)
__global__ __launch_bounds__(256) void gemm_qp_sl(
    const uint4* __restrict__ A,   // slotA [8192][192]
    const uint4* __restrict__ Bm,  // Pb [768][96]
    const uint4* __restrict__ Wc,  // Wcomb [128][192]
    const float* __restrict__ u,
    float* __restrict__ qp,        // [8192][768]
    float* __restrict__ Cpart0)    // [8192][128]
{
    __shared__ uint4 sA[256];
    __shared__ uint4 sB[512];

    int bid = blockIdx.x;
    int t = threadIdx.x;
    int lane = t & 63, wave = t >> 6;
    int wm = wave >> 1, wn = wave & 1;
    int l16 = lane & 15, lk = lane >> 4;
    int srow = lane >> 2, schk = lane & 3;

    if (bid >= 768) {            // ---- slot-left: 32x128 tile ----
        int mt = bid - 768;      // 0..255
        const uint4* Ag  = A + (size_t)(mt * 32 + wave * 16 + srow) * 192 + schk; // waves 0,1 only
        const uint4* Bg0 = Wc + (size_t)(wave * 32 + srow) * 192 + schk;
        const uint4* Bg1 = Bg0 + (size_t)16 * 192;
        uint4* sB0 = &sB[wave * 128];
        uint4* sB1 = &sB[wave * 128 + 64];

        f32x4 acc[4] = {};
        for (int k0 = 0; k0 < 96; k0 += 4) {
            if (wave < 2) gload16(Ag + k0, &sA[wave * 64]);
            gload16(Bg0 + k0, sB0);
            gload16(Bg1 + k0, sB1);
            __syncthreads();
            bf16x8 af = *reinterpret_cast<const bf16x8*>(&sA[(wm * 16 + l16) * 4 + lk]);
            bf16x8 bfr[4];
#pragma unroll
            for (int j = 0; j < 4; j++)
                bfr[j] = *reinterpret_cast<const bf16x8*>(&sB[(wn * 64 + j * 16 + l16) * 4 + lk]);
#pragma unroll
            for (int j = 0; j < 4; j++)
                acc[j] = MF(af, bfr[j], acc[j]);
            __syncthreads();
        }
#pragma unroll
        for (int j = 0; j < 4; j++) {
            int col = wn * 64 + j * 16 + l16;
#pragma unroll
            for (int q = 0; q < 4; q++) {
                int row = mt * 32 + wm * 16 + lk * 4 + q;
                Cpart0[(size_t)row * 128 + col] = acc[j][q];
            }
        }
        return;
    }

    // ---- qp: 64x128 tile, XCD swizzle over 768 ----
    bid = (bid & 7) * 96 + (bid >> 3);
    int mt = bid / 6, nt = bid % 6;

    const uint4* Ag  = A + (size_t)(mt * 64 + wave * 16 + srow) * 192 + schk;
    const uint4* Bg0 = Bm + (size_t)(nt * 128 + wave * 32 + srow) * 96 + schk;
    const uint4* Bg1 = Bg0 + (size_t)16 * 96;
    uint4* sAp = &sA[wave * 64];
    uint4* sB0 = &sB[wave * 128];
    uint4* sB1 = &sB[wave * 128 + 64];

    f32x4 acc[2][4] = {};

    for (int k0 = 0; k0 < 96; k0 += 4) {
        gload16(Ag + k0, sAp);
        gload16(Bg0 + k0, sB0);
        gload16(Bg1 + k0, sB1);
        __syncthreads();
        bf16x8 af[2], bfr[4];
#pragma unroll
        for (int i = 0; i < 2; i++)
            af[i] = *reinterpret_cast<const bf16x8*>(&sA[(wm * 32 + i * 16 + l16) * 4 + lk]);
#pragma unroll
        for (int j = 0; j < 4; j++)
            bfr[j] = *reinterpret_cast<const bf16x8*>(&sB[(wn * 64 + j * 16 + l16) * 4 + lk]);
#pragma unroll
        for (int i = 0; i < 2; i++)
#pragma unroll
            for (int j = 0; j < 4; j++)
                acc[i][j] = MF(af[i], bfr[j], acc[i][j]);
        __syncthreads();
    }

#pragma unroll
    for (int i = 0; i < 2; i++)
#pragma unroll
        for (int j = 0; j < 4; j++) {
            int col = nt * 128 + wn * 64 + j * 16 + l16;
            float add = u[col];
#pragma unroll
            for (int q = 0; q < 4; q++) {
                int row = mt * 64 + wm * 32 + i * 16 + lk * 4 + q;
                qp[(size_t)row * HH + col] = acc[i][j][q] + add;
            }
        }
}

// ================= K5: flash attention (single pass, online softmax) ========
__global__ __launch_bounds__(256) void attn2_kernel(
    const float* __restrict__ qp,        // [8192][768] f32
    const float* __restrict__ res_all,   // [B*S][768] f32
    const int* __restrict__ starts,
    const int* __restrict__ lens,
    unsigned short* __restrict__ slotA)  // [8192][1536], writes cols 768..1535
{
    int bid = blockIdx.x;
    bid = (bid & 7) * 256 + (bid >> 3);              // 2048 = 8 x 256
    int gw = bid * 4 + (threadIdx.x >> 6);
    int lane = threadIdx.x & 63;
    int b = gw >> 8;
    int s0 = starts[gw];
    int sl = lens[gw];                               // 1..7, wave-uniform

    unsigned short* dst = slotA + (size_t)gw * 1536 + 768 + lane * 12;

    if (sl == 1) {                                   // word = first; xbar half = 0
        ushort4 z = {0, 0, 0, 0};
#pragma unroll
        for (int c = 0; c < 3; c++) *reinterpret_cast<ushort4*>(&dst[c * 4]) = z;
        return;
    }

    const float* qrow = qp + (size_t)gw * HH + lane * 12;
    float q[12];
#pragma unroll
    for (int c = 0; c < 3; c++) {
        float4 v = *reinterpret_cast<const float4*>(&qrow[c * 4]);
        q[c * 4 + 0] = v.x; q[c * 4 + 1] = v.y; q[c * 4 + 2] = v.z; q[c * 4 + 3] = v.w;
    }

    // online softmax: one pass over rows
    float m = -1e30f, ssum = 0.f;
    float acc[12];
#pragma unroll
    for (int i = 0; i < 12; i++) acc[i] = 0.f;

    for (int k = 0; k < LL; k++) {
        if (k > sl) break;                           // uniform branch
        int s = s0 + k; if (s > SS - 1) s = SS - 1;
        const float* xr = res_all + (size_t)(b * SS + s) * HH + lane * 12;
        float x[12];
        float partial = 0.f;
#pragma unroll
        for (int c = 0; c < 3; c++) {
            float4 v = *reinterpret_cast<const float4*>(&xr[c * 4]);
            x[c * 4 + 0] = v.x; x[c * 4 + 1] = v.y;
            x[c * 4 + 2] = v.z; x[c * 4 + 3] = v.w;
            partial += q[c * 4 + 0] * v.x + q[c * 4 + 1] * v.y
                     + q[c * 4 + 2] * v.z + q[c * 4 + 3] * v.w;
        }
#pragma unroll
        for (int off = 32; off > 0; off >>= 1) partial += __shfl_xor(partial, off);

        float mnew = (partial > m) ? partial : m;
        float scale = __expf(m - mnew);
        float e = __expf(partial - mnew);
        ssum = ssum * scale + e;
#pragma unroll
        for (int i = 0; i < 12; i++) acc[i] = acc[i] * scale + e * x[i];
        m = mnew;
    }

    float inv = 1.f / ssum;
#pragma unroll
    for (int c = 0; c < 3; c++) {
        ushort4 o;
        o.x = f2bf(acc[c * 4 + 0] * inv); o.y = f2bf(acc[c * 4 + 1] * inv);
        o.z = f2bf(acc[c * 4 + 2] * inv); o.w = f2bf(acc[c * 4 + 3] * inv);
        *reinterpret_cast<ushort4*>(&dst[c * 4]) = o;
    }
}

// ================= K6': slot-right GEMM + merge (32x128 tiles, 256 blocks) ==
__global__ __launch_bounds__(256) void gemm_slot_r(
    const uint4* __restrict__ A,    // slotA [8192][192]
    const uint4* __restrict__ Bm,   // Wcomb [128][192]
    const float* __restrict__ Cpart0,
    const float* __restrict__ bias, const float* __restrict__ wsbv,
    const int* __restrict__ lens,
    float* __restrict__ outsf)      // [8192][121]
{
    __shared__ uint4 sA[128];   // 32 rows
    __shared__ uint4 sB[512];   // 128 rows

    int mt = blockIdx.x;
    int t = threadIdx.x;
    int lane = t & 63, wave = t >> 6;
    int wm = wave >> 1, wn = wave & 1;
    int l16 = lane & 15, lk = lane >> 4;
    int srow = lane >> 2, schk = lane & 3;

    const uint4* Ag  = A + (size_t)(mt * 32 + wave * 16 + srow) * 192 + 96 + schk;
    const uint4* Bg0 = Bm + (size_t)(wave * 32 + srow) * 192 + 96 + schk;
    const uint4* Bg1 = Bg0 + (size_t)16 * 192;
    uint4* sB0 = &sB[wave * 128];
    uint4* sB1 = &sB[wave * 128 + 64];

    f32x4 acc[4] = {};

    for (int k0 = 0; k0 < 96; k0 += 4) {
        if (wave < 2) gload16(Ag + k0, &sA[wave * 64]);
        gload16(Bg0 + k0, sB0);
        gload16(Bg1 + k0, sB1);
        __syncthreads();
        bf16x8 af = *reinterpret_cast<const bf16x8*>(&sA[(wm * 16 + l16) * 4 + lk]);
        bf16x8 bfr[4];
#pragma unroll
        for (int j = 0; j < 4; j++)
            bfr[j] = *reinterpret_cast<const bf16x8*>(&sB[(wn * 64 + j * 16 + l16) * 4 + lk]);
#pragma unroll
        for (int j = 0; j < 4; j++)
            acc[j] = MF(af, bfr[j], acc[j]);
        __syncthreads();
    }

#pragma unroll
    for (int j = 0; j < 4; j++) {
        int col = wn * 64 + j * 16 + l16;
        if (col < NSLOT) {
            float bc = bias[col], wv = wsbv[col];
#pragma unroll
            for (int q = 0; q < 4; q++) {
                int row = mt * 32 + wm * 16 + lk * 4 + q;
                float v = acc[j][q] + Cpart0[(size_t)row * 128 + col]
                        + bc + ((lens[row] > 1) ? wv : 0.f);
                outsf[(size_t)row * NSLOT + col] = v;
            }
        }
    }
}

// ---------------- launch ----------------
extern "C" void kernel_launch(void* const* d_in, const int* in_sizes, int n_in,
                              void* d_out, int out_size, void* d_ws, size_t ws_size,
                              hipStream_t stream) {
    const float* res_all    = (const float*)d_in[0];
    const float* res        = (const float*)d_in[1];
    const int*   starts     = (const int*)d_in[2];
    const int*   lens       = (const int*)d_in[3];
    const float* Wsq_w      = (const float*)d_in[4];
    const float* Wsq_b      = (const float*)d_in[5];
    const float* Wsk_w      = (const float*)d_in[6];
    const float* Wsk_b      = (const float*)d_in[7];
    const float* Wsv_w      = (const float*)d_in[8];
    const float* Wsv_b      = (const float*)d_in[9];
    const float* lin_id_w   = (const float*)d_in[10];
    const float* lin_id_b   = (const float*)d_in[11];
    const float* lin_slot_w = (const float*)d_in[12];
    const float* lin_slot_b = (const float*)d_in[13];
    float* out = (float*)d_out;
    (void)Wsk_b;  // softmax-invariant (constant over k)

    char* ws = (char*)d_ws;
    unsigned short* slotA     = (unsigned short*)(ws + 0);          // 8192x1536 bf16
    float*          qp        = (float*)(ws + 25165824);            // 8192x768 f32
    unsigned short* WkT_hi    = (unsigned short*)(ws + 50331648);
    unsigned short* WkT_lo    = (unsigned short*)(ws + 51511296);
    unsigned short* WqT_hi    = (unsigned short*)(ws + 52690944);
    unsigned short* WqT_lo    = (unsigned short*)(ws + 53870592);
    unsigned short* WvT       = (unsigned short*)(ws + 55050240);
    unsigned short* Pb        = (unsigned short*)(ws + 56229888);   // 768^2 bf16
    unsigned short* Wcomb     = (unsigned short*)(ws + 57409536);   // 128x1536 bf16
    float*          u         = (float*)(ws + 57802752);            // 768
    float*          wsbv      = (float*)(ws + 57805824);            // 128
    float*          u_part    = (float*)(ws + 57806336);            // 12x768
    float*          wsbv_part = (float*)(ws + 57843200);            // 3x128
    float*          Ppart     = (float*)(ws + 57845760);            // 8x768x768 f32
    float*          WRpart    = (float*)(ws + 76720128);            // 8x128x768 f32
    float*          Cpart0    = (float*)(ws + 79865856);            // 8192x128 f32

    // K1: weight prep
    prep_w<<<816, 256, 0, stream>>>(
        Wsk_w, Wsq_w, Wsv_w, lin_slot_w, Wsq_b, Wsv_b,
        WkT_hi, WkT_lo, WqT_hi, WqT_lo, WvT, Wcomb,
        u_part, wsbv_part);

    // K2: weight GEMMs + gather + res_id
    gemm_weights<<<2592, 256, 0, stream>>>(
        (const uint4*)WkT_hi, (const uint4*)WkT_lo,
        (const uint4*)WqT_hi, (const uint4*)WqT_lo,
        (const uint4*)WvT, (const uint4*)Wcomb,
        res_all, starts, res, lin_id_w, lin_id_b,
        Ppart, WRpart, slotA, out);

    // K3: reductions
    psum_kernel<<<676, 256, 0, stream>>>(
        (const float4*)Ppart, (ushort4*)Pb, (const float4*)WRpart, Wcomb,
        u_part, u, wsbv_part, wsbv);

    // K4': qp GEMM + slot-left GEMM (overlapped in one launch)
    gemm_qp_sl<<<1024, 256, 0, stream>>>((const uint4*)slotA, (const uint4*)Pb,
                                         (const uint4*)Wcomb, u, qp, Cpart0);

    // K5: flash attention -> slotA right half
    attn2_kernel<<<2048, 256, 0, stream>>>(qp, res_all, starts, lens, slotA);

    // K6': slot-right GEMM + merge -> out
    gemm_slot_r<<<256, 256, 0, stream>>>((const uint4*)slotA, (const uint4*)Wcomb,
                                         Cpart0, lin_slot_b, wsbv, lens, out + 832);
}